// Round 7
// baseline (348.643 us; speedup 1.0000x reference)
//
#include <hip/hip_runtime.h>
#include <math.h>

#define N_NODES 100000
#define N_EDGES 1600000
#define HEADS 4
#define NBKT ((N_NODES + 255) / 256)
#define CHUNK_E 4096
#define NCHUNK ((N_EDGES + CHUNK_E - 1) / CHUNK_E)
#define GN ((N_NODES + 255) / 256)
#define SUM_ROWS 16
#define NRB ((NCHUNK + SUM_ROWS - 1) / SUM_ROWS)

typedef unsigned short ushort_t;
typedef unsigned char  uchar_t;

__device__ __forceinline__ ushort_t f2bf(float x) {
    unsigned u = __float_as_uint(x);
    u += 0x7FFF + ((u >> 16) & 1);
    return (ushort_t)(u >> 16);
}
__device__ __forceinline__ float bf2f(ushort_t v) {
    return __uint_as_float(((unsigned)v) << 16);
}
__device__ __forceinline__ void unpack2(unsigned u, float& lo, float& hi) {
    lo = __uint_as_float(u << 16);
    hi = __uint_as_float(u & 0xffff0000u);
}
// unsigned e5m3 fp8 (ReLU outputs only)
__device__ __forceinline__ uchar_t f2fp8(float x) {
    if (x <= 0.0f) return 0;
    unsigned u = __float_as_uint(x) + (1u << 19);
    int e = (int)(u >> 23) - 127 + 15;
    if (e <= 0) return 0;
    if (e > 31) return (uchar_t)255;
    return (uchar_t)((e << 3) | ((u >> 20) & 7));
}
__device__ __forceinline__ float fp8d(uchar_t b) {
    unsigned v = (((unsigned)(b >> 3) + 112u) << 23) | ((unsigned)(b & 7) << 20);
    return (b == 0) ? 0.0f : __uint_as_float(v);
}

// R22 combined-record layout (per node, 64B, line-aligned):
//   bytes [0,32):  feature row (bf16 x16  OR  fp8 x32)
//   bytes [32,48): es[4] = exp(p[h]) fp32
//   bytes [48,64): pad (never read)
// One random 64B line per edge serves BOTH the q-phase es gather and the
// accumulate row gather (same s, same CU, CHUNK=512 lines fit 32KB L1).

// ---------------- K1: per-chunk histogram rows + crec1 build + bucket_cnt zero ----

__global__ __launch_bounds__(256) void bhist_pcast_kernel(
        const int* __restrict__ dst, int* __restrict__ hist_rows,
        const float* __restrict__ x, const float* __restrict__ U,
        char* __restrict__ crec1, int* __restrict__ bucket_cnt)
{
    __shared__ int h[NBKT];
    if (blockIdx.x < NCHUNK) {
        for (int i = threadIdx.x; i < NBKT; i += 256) h[i] = 0;
        __syncthreads();
        int base = blockIdx.x * CHUNK_E;
        #pragma unroll
        for (int j = 0; j < CHUNK_E / 256; j++) {
            int e = base + j * 256 + threadIdx.x;
            if (e < N_EDGES) atomicAdd(&h[dst[e] >> 8], 1);
        }
        __syncthreads();
        for (int i = threadIdx.x; i < NBKT; i += 256)
            hist_rows[(size_t)blockIdx.x * NBKT + i] = h[i];
    } else if (blockIdx.x < NCHUNK + GN) {
        int n = (blockIdx.x - NCHUNK) * 256 + threadIdx.x;
        if (n >= N_NODES) return;
        float a0 = 0, a1 = 0, a2 = 0, a3 = 0;
        const float* hr = x + (size_t)n * 16;
        float xv[16];
        #pragma unroll
        for (int f = 0; f < 16; f++) {
            xv[f] = hr[f];
            a0 += xv[f] * U[f * 4 + 0];
            a1 += xv[f] * U[f * 4 + 1];
            a2 += xv[f] * U[f * 4 + 2];
            a3 += xv[f] * U[f * 4 + 3];
        }
        char* rec = crec1 + (size_t)n * 64;
        #pragma unroll
        for (int j = 0; j < 4; j++) {
            ushort4 u;
            u.x = f2bf(xv[4 * j + 0]); u.y = f2bf(xv[4 * j + 1]);
            u.z = f2bf(xv[4 * j + 2]); u.w = f2bf(xv[4 * j + 3]);
            *(ushort4*)(rec + 8 * j) = u;
        }
        *(float4*)(rec + 32) =
            make_float4(__expf(a0), __expf(a1), __expf(a2), __expf(a3));
    } else {
        for (int i = threadIdx.x; i < NBKT; i += 256) bucket_cnt[i] = 0;
    }
}

// ---------------- K2a: parallel column-sum ----

__global__ __launch_bounds__(256) void ksum_kernel(const int* __restrict__ hist_rows,
                                                   int* __restrict__ bucket_cnt) {
    int r0 = blockIdx.x * SUM_ROWS;
    int r1 = min(r0 + SUM_ROWS, NCHUNK);
    for (int i = threadIdx.x; i < NBKT; i += 256) {
        int v = 0;
        for (int r = r0; r < r1; r++) v += hist_rows[(size_t)r * NBKT + i];
        if (v) atomicAdd(&bucket_cnt[i], v);
    }
}

// ---------------- K2b: exclusive scan -> base + cursor ----

__global__ __launch_bounds__(512) void bscan_kernel(const int* __restrict__ bucket_cnt,
                                                    int* __restrict__ bucket_base,
                                                    int* __restrict__ bucket_cursor) {
    __shared__ int tmp[512];
    int i = threadIdx.x;
    int v = (i < NBKT) ? bucket_cnt[i] : 0;
    tmp[i] = v;
    __syncthreads();
    for (int off = 1; off < 512; off <<= 1) {
        int t = (i >= off) ? tmp[i - off] : 0;
        __syncthreads();
        tmp[i] += t;
        __syncthreads();
    }
    int excl = tmp[i] - v;
    if (i < NBKT) { bucket_base[i] = excl; bucket_cursor[i] = excl; }
    if (i == NBKT) bucket_base[NBKT] = N_EDGES;
}

// ---------------- K3: partition into coarse buckets; packed = (dst&255)<<20 | src ----

__global__ __launch_bounds__(256) void partition_kernel(const int* __restrict__ src,
                                                        const int* __restrict__ dst,
                                                        int* __restrict__ bucket_cursor,
                                                        int* __restrict__ csr_tmp) {
    constexpr int EPT = CHUNK_E / 256;
    __shared__ int h[NBKT];
    __shared__ int gbase[NBKT];
    __shared__ int rcnt[NBKT];
    for (int i = threadIdx.x; i < NBKT; i += 256) { h[i] = 0; rcnt[i] = 0; }
    __syncthreads();
    int base = blockIdx.x * CHUNK_E;
    int d[EPT], s[EPT];
    #pragma unroll
    for (int j = 0; j < EPT; j++) {
        int e = base + j * 256 + threadIdx.x;
        d[j] = (e < N_EDGES) ? dst[e] : -1;
        s[j] = (e < N_EDGES) ? src[e] : 0;
        if (d[j] >= 0) atomicAdd(&h[d[j] >> 8], 1);
    }
    __syncthreads();
    for (int i = threadIdx.x; i < NBKT; i += 256)
        if (h[i]) gbase[i] = atomicAdd(&bucket_cursor[i], h[i]);
    __syncthreads();
    #pragma unroll
    for (int j = 0; j < EPT; j++) {
        if (d[j] >= 0) {
            int b = d[j] >> 8;
            int r = atomicAdd(&rcnt[b], 1);
            csr_tmp[gbase[b] + r] = ((d[j] & 255) << 20) | s[j];
        }
    }
}

// ---------------- K4: per-bucket build; csr_src keeps dlow packed ----

__global__ __launch_bounds__(256) void bucket_build_kernel(const int* __restrict__ bucket_base,
                                                           const int* __restrict__ csr_tmp,
                                                           int* __restrict__ rowptr,
                                                           int* __restrict__ csr_src) {
    __shared__ int cnt[256];
    __shared__ int tscan[256];
    __shared__ int exc[256];
    __shared__ int stage[8192];
    int b = blockIdx.x;
    int rbeg = bucket_base[b], rend = bucket_base[b + 1];
    int sz = rend - rbeg;
    int tid = threadIdx.x;

    cnt[tid] = 0;
    __syncthreads();
    for (int k = rbeg + tid; k < rend; k += 256) atomicAdd(&cnt[csr_tmp[k] >> 20], 1);
    __syncthreads();
    int v = cnt[tid];
    tscan[tid] = v;
    __syncthreads();
    for (int off = 1; off < 256; off <<= 1) {
        int t = (tid >= off) ? tscan[tid - off] : 0;
        __syncthreads();
        tscan[tid] += t;
        __syncthreads();
    }
    int ex = tscan[tid] - v;
    int node = b * 256 + tid;
    if (node < N_NODES) rowptr[node] = rbeg + ex;
    if (b == 0 && tid == 0) rowptr[N_NODES] = N_EDGES;
    exc[tid] = ex;
    cnt[tid] = 0;
    __syncthreads();

    if (sz <= 8192) {
        for (int k = rbeg + tid; k < rend; k += 256) {
            int pk = csr_tmp[k];
            int dl = pk >> 20;
            int r  = atomicAdd(&cnt[dl], 1);
            stage[exc[dl] + r] = pk;
        }
        __syncthreads();
        for (int i = tid; i < sz; i += 256) csr_src[rbeg + i] = stage[i];
    } else {
        for (int k = rbeg + tid; k < rend; k += 256) {
            int pk = csr_tmp[k];
            int dl = pk >> 20;
            int r  = atomicAdd(&cnt[dl], 1);
            csr_src[rbeg + exc[dl] + r] = pk;
        }
    }
}

// ---------------- fused conv (conv1/conv2): R22 = R21 two-phase + 64B
// combined records.  q-phase gathers es from crec_in+s*64+32 (1 line miss,
// warms line); accumulate gathers row slices from the SAME line (L1 hit,
// CHUNK=512 lines = 32KB = L1).  Output row + esnext both go to crec_out.

template<int FIN, int FOUT, int OUT_FP8>
__global__ __launch_bounds__(256) void conv_fused_kernel(
        const int* __restrict__ rowptr, const int* __restrict__ csr_src,
        const char* __restrict__ crec_in,     // [N,64B] {bf16 row, es, pad}
        const float* __restrict__ cvec,
        const float* __restrict__ W,          // [FIN, 4*FOUT]
        const float* __restrict__ b,          // [FOUT]
        char* __restrict__ crec_out)          // [N,64B] {row, esnext, pad}
{
    constexpr int LPN   = FIN / 4;            // 4
    constexpr int NPB   = 256 / LPN;          // 64
    constexpr int CHUNK = 512;
    constexpr int K     = 4 * FIN;            // 64
    constexpr int ZK    = K + 4;
    constexpr int HS    = FOUT + 1;
    constexpr int WSZ   = K * FOUT;
    constexpr int UNION_A = CHUNK * 16 + CHUNK * 4;
    constexpr int UNION_B = NPB * ZK * 4 + NPB * HS * 4;
    constexpr int UNION   = UNION_A > UNION_B ? UNION_A : UNION_B;

    __shared__ int    sbeg[NPB + 1];
    __shared__ __align__(16) float4 pds[NPB];    // ed per local node
    __shared__ __align__(16) float  Ws[WSZ];
    __shared__ __align__(16) char ubuf[UNION];
    float4* qs    = (float4*)ubuf;
    int*    ssrc  = (int*)(ubuf + CHUNK * 16);
    float*  ztile = (float*)ubuf;
    float*  hout  = (float*)(ubuf + NPB * ZK * 4);

    int tid  = threadIdx.x;
    int nloc = tid / LPN;
    int fl   = (tid - nloc * LPN) * 4;
    int n0   = blockIdx.x * NPB;
    int dbase = n0 & 255;

    float ec0 = __expf(cvec[0]), ec1 = __expf(cvec[1]);
    float ec2 = __expf(cvec[2]), ec3 = __expf(cvec[3]);

    for (int i = tid; i <= NPB; i += 256) {
        int idx = n0 + i;
        sbeg[i] = rowptr[idx > N_NODES ? N_NODES : idx];
    }
    for (int i = tid; i < NPB; i += 256) {
        int idx = n0 + i;
        float4 e = *(const float4*)(crec_in +
            (size_t)(idx < N_NODES ? idx : N_NODES - 1) * 64 + 32);
        pds[i] = make_float4(ec0 / e.x, ec1 / e.y, ec2 / e.z, ec3 / e.w);
    }
    for (int i = tid; i < WSZ; i += 256) {
        int f = i / (4 * FOUT);
        int r = i - f * (4 * FOUT);
        int h = r / FOUT;
        int o = r - h * FOUT;
        Ws[(h * FIN + f) * FOUT + o] = W[i];
    }
    __syncthreads();

    int BB = sbeg[0], BE = sbeg[NPB];
    int beg = sbeg[nloc], end = sbeg[nloc + 1];

    float4 acc0 = make_float4(0, 0, 0, 0), acc1 = acc0, acc2 = acc0, acc3 = acc0;

    for (int cbase = BB; cbase < BE; cbase += CHUNK) {
        int cend = min(cbase + CHUNK, BE);
        __syncthreads();
        for (int k = cbase + tid; k < cend; k += 256) {
            int pk = csr_src[k];
            int s  = pk & ((1 << 20) - 1);
            int nl = (pk >> 20) - dbase;
            float4 e  = *(const float4*)(crec_in + (size_t)s * 64 + 32);
            float4 ed = pds[nl];
            float w0 = e.x * ed.x;
            float w1 = e.y * ed.y;
            float w2 = e.z * ed.z;
            float w3 = e.w * ed.w;
            float deg = (float)(sbeg[nl + 1] - sbeg[nl]);
            float inv = 1.0f / (fmaxf(deg, 1.0f) * (w0 + w1 + w2 + w3));
            qs[k - cbase]   = make_float4(w0 * inv, w1 * inv, w2 * inv, w3 * inv);
            ssrc[k - cbase] = s;
        }
        __syncthreads();
        int kb = (beg > cbase ? beg : cbase) - cbase;
        int ke = (end < cend ? end : cend) - cbase;
        int k = kb;
        for (; k + 4 <= ke; k += 4) {
            uint2 r[4];
            #pragma unroll
            for (int j = 0; j < 4; j++)
                r[j] = *(const uint2*)(crec_in + (size_t)ssrc[k + j] * 64 + fl * 2);
            float xv[4][4];
            #pragma unroll
            for (int j = 0; j < 4; j++) {
                unpack2(r[j].x, xv[j][0], xv[j][1]);
                unpack2(r[j].y, xv[j][2], xv[j][3]);
            }
            #pragma unroll
            for (int j = 0; j < 4; j++) {
                float4 q = qs[k + j];
                acc0.x += q.x * xv[j][0]; acc0.y += q.x * xv[j][1];
                acc0.z += q.x * xv[j][2]; acc0.w += q.x * xv[j][3];
                acc1.x += q.y * xv[j][0]; acc1.y += q.y * xv[j][1];
                acc1.z += q.y * xv[j][2]; acc1.w += q.y * xv[j][3];
                acc2.x += q.z * xv[j][0]; acc2.y += q.z * xv[j][1];
                acc2.z += q.z * xv[j][2]; acc2.w += q.z * xv[j][3];
                acc3.x += q.w * xv[j][0]; acc3.y += q.w * xv[j][1];
                acc3.z += q.w * xv[j][2]; acc3.w += q.w * xv[j][3];
            }
        }
        for (; k < ke; k++) {
            float x0, x1, x2, x3;
            uint2 r = *(const uint2*)(crec_in + (size_t)ssrc[k] * 64 + fl * 2);
            unpack2(r.x, x0, x1);
            unpack2(r.y, x2, x3);
            float4 q = qs[k];
            acc0.x += q.x * x0; acc0.y += q.x * x1; acc0.z += q.x * x2; acc0.w += q.x * x3;
            acc1.x += q.y * x0; acc1.y += q.y * x1; acc1.z += q.y * x2; acc1.w += q.y * x3;
            acc2.x += q.z * x0; acc2.y += q.z * x1; acc2.z += q.z * x2; acc2.w += q.z * x3;
            acc3.x += q.w * x0; acc3.y += q.w * x1; acc3.z += q.w * x2; acc3.w += q.w * x3;
        }
    }

    __syncthreads();
    {
        float* zr = ztile + nloc * ZK;
        *(float4*)(zr + 0 * FIN + fl) = acc0;
        *(float4*)(zr + 1 * FIN + fl) = acc1;
        *(float4*)(zr + 2 * FIN + fl) = acc2;
        *(float4*)(zr + 3 * FIN + fl) = acc3;
    }
    __syncthreads();

    constexpr int OQ  = FOUT / 4;
    constexpr int QPT = (NPB * OQ) / 256;
    #pragma unroll
    for (int rq = 0; rq < QPT; rq++) {
        int idx = tid + 256 * rq;
        int j   = idx / OQ;
        int o4  = idx - j * OQ;
        float4 acc = *(const float4*)(b + 4 * o4);
        const float* zr = ztile + j * ZK;
        #pragma unroll 4
        for (int kq = 0; kq < K / 4; kq++) {
            float4 zt = *(const float4*)(zr + 4 * kq);
            #pragma unroll
            for (int jj = 0; jj < 4; jj++) {
                float4 wv = *(const float4*)(Ws + (4 * kq + jj) * FOUT + 4 * o4);
                float s = (&zt.x)[jj];
                acc.x += s * wv.x;
                acc.y += s * wv.y;
                acc.z += s * wv.z;
                acc.w += s * wv.w;
            }
        }
        acc.x = fmaxf(acc.x, 0.0f);
        acc.y = fmaxf(acc.y, 0.0f);
        acc.z = fmaxf(acc.z, 0.0f);
        acc.w = fmaxf(acc.w, 0.0f);
        float* hr = hout + j * HS + 4 * o4;
        hr[0] = acc.x; hr[1] = acc.y; hr[2] = acc.z; hr[3] = acc.w;
        int nn = n0 + j;
        if (nn < N_NODES) {
            if (OUT_FP8) {
                unsigned pk = (unsigned)f2fp8(acc.x) | ((unsigned)f2fp8(acc.y) << 8) |
                              ((unsigned)f2fp8(acc.z) << 16) | ((unsigned)f2fp8(acc.w) << 24);
                *(unsigned*)(crec_out + (size_t)nn * 64 + 4 * o4) = pk;
            } else {
                ushort4 u;
                u.x = f2bf(acc.x); u.y = f2bf(acc.y); u.z = f2bf(acc.z); u.w = f2bf(acc.w);
                *(ushort4*)(crec_out + (size_t)nn * 64 + 8 * o4) = u;
            }
        }
    }

    __syncthreads();
    if (tid < NPB) {
        int nn = n0 + tid;
        if (nn < N_NODES) {
            // Uloc folded: read Unext from hout side?  No — Unext needed.
        }
    }
}

// pnext epilogue split out would need Unext; keep it fused via a second pass:
// (see conv_fused_kernel2 below — actually we keep the original fused form)

// ---------------- zgather (conv3, fp8 in crec3), z out bf16; R22 records ----

template<int FIN>
__global__ __launch_bounds__(256) void zgather_kernel(
        const int* __restrict__ rowptr, const int* __restrict__ csr_src,
        const char* __restrict__ crec_in,  // [N,64B] {fp8 row 32B, es, pad}
        const float* __restrict__ cvec,
        ushort_t* __restrict__ z)          // [N, 4*FIN] bf16
{
    constexpr int LPN   = FIN / 4;         // 8
    constexpr int NPB   = 256 / LPN;       // 32
    constexpr int CHUNK = 512;
    __shared__ int    sbeg[NPB + 1];
    __shared__ __align__(16) float4 pds[NPB];
    __shared__ __align__(16) float4 qs[CHUNK];
    __shared__ int    ssrc[CHUNK];

    int tid  = threadIdx.x;
    int nloc = tid / LPN;
    int fl   = (tid - nloc * LPN) * 4;     // feature offset; fp8 => byte offset
    int n0   = blockIdx.x * NPB;
    int n    = n0 + nloc;
    int dbase = n0 & 255;

    float ec0 = __expf(cvec[0]), ec1 = __expf(cvec[1]);
    float ec2 = __expf(cvec[2]), ec3 = __expf(cvec[3]);

    for (int i = tid; i <= NPB; i += 256) {
        int idx = n0 + i;
        sbeg[i] = rowptr[idx > N_NODES ? N_NODES : idx];
    }
    for (int i = tid; i < NPB; i += 256) {
        int idx = n0 + i;
        float4 e = *(const float4*)(crec_in +
            (size_t)(idx < N_NODES ? idx : N_NODES - 1) * 64 + 32);
        pds[i] = make_float4(ec0 / e.x, ec1 / e.y, ec2 / e.z, ec3 / e.w);
    }
    __syncthreads();

    int BB = sbeg[0], BE = sbeg[NPB];
    int beg = sbeg[nloc], end = sbeg[nloc + 1];

    float4 acc0 = make_float4(0, 0, 0, 0), acc1 = acc0, acc2 = acc0, acc3 = acc0;

    for (int cbase = BB; cbase < BE; cbase += CHUNK) {
        int cend = min(cbase + CHUNK, BE);
        __syncthreads();
        for (int k = cbase + tid; k < cend; k += 256) {
            int pk = csr_src[k];
            int s  = pk & ((1 << 20) - 1);
            int nl = (pk >> 20) - dbase;
            float4 e  = *(const float4*)(crec_in + (size_t)s * 64 + 32);
            float4 ed = pds[nl];
            float w0 = e.x * ed.x;
            float w1 = e.y * ed.y;
            float w2 = e.z * ed.z;
            float w3 = e.w * ed.w;
            float deg = (float)(sbeg[nl + 1] - sbeg[nl]);
            float inv = 1.0f / (fmaxf(deg, 1.0f) * (w0 + w1 + w2 + w3));
            qs[k - cbase]   = make_float4(w0 * inv, w1 * inv, w2 * inv, w3 * inv);
            ssrc[k - cbase] = s;
        }
        __syncthreads();
        int kb = (beg > cbase ? beg : cbase) - cbase;
        int ke = (end < cend ? end : cend) - cbase;
        int k = kb;
        for (; k + 4 <= ke; k += 4) {
            unsigned r[4];
            #pragma unroll
            for (int j = 0; j < 4; j++)
                r[j] = *(const unsigned*)(crec_in + (size_t)ssrc[k + j] * 64 + fl);
            float xv[4][4];
            #pragma unroll
            for (int j = 0; j < 4; j++) {
                xv[j][0] = fp8d((uchar_t)(r[j] & 255));
                xv[j][1] = fp8d((uchar_t)((r[j] >> 8) & 255));
                xv[j][2] = fp8d((uchar_t)((r[j] >> 16) & 255));
                xv[j][3] = fp8d((uchar_t)(r[j] >> 24));
            }
            #pragma unroll
            for (int j = 0; j < 4; j++) {
                float4 q = qs[k + j];
                acc0.x += q.x * xv[j][0]; acc0.y += q.x * xv[j][1];
                acc0.z += q.x * xv[j][2]; acc0.w += q.x * xv[j][3];
                acc1.x += q.y * xv[j][0]; acc1.y += q.y * xv[j][1];
                acc1.z += q.y * xv[j][2]; acc1.w += q.y * xv[j][3];
                acc2.x += q.z * xv[j][0]; acc2.y += q.z * xv[j][1];
                acc2.z += q.z * xv[j][2]; acc2.w += q.z * xv[j][3];
                acc3.x += q.w * xv[j][0]; acc3.y += q.w * xv[j][1];
                acc3.z += q.w * xv[j][2]; acc3.w += q.w * xv[j][3];
            }
        }
        for (; k < ke; k++) {
            unsigned r = *(const unsigned*)(crec_in + (size_t)ssrc[k] * 64 + fl);
            float x0 = fp8d((uchar_t)(r & 255));
            float x1 = fp8d((uchar_t)((r >> 8) & 255));
            float x2 = fp8d((uchar_t)((r >> 16) & 255));
            float x3 = fp8d((uchar_t)(r >> 24));
            float4 q = qs[k];
            acc0.x += q.x * x0; acc0.y += q.x * x1; acc0.z += q.x * x2; acc0.w += q.x * x3;
            acc1.x += q.y * x0; acc1.y += q.y * x1; acc1.z += q.y * x2; acc1.w += q.y * x3;
            acc2.x += q.z * x0; acc2.y += q.z * x1; acc2.z += q.z * x2; acc2.w += q.z * x3;
            acc3.x += q.w * x0; acc3.y += q.w * x1; acc3.z += q.w * x2; acc3.w += q.w * x3;
        }
    }

    if (n < N_NODES) {
        size_t base = (size_t)n * (4 * FIN) + fl;
        ushort4 u;
        u.x = f2bf(acc0.x); u.y = f2bf(acc0.y); u.z = f2bf(acc0.z); u.w = f2bf(acc0.w);
        *(ushort4*)(z + base) = u;
        u.x = f2bf(acc1.x); u.y = f2bf(acc1.y); u.z = f2bf(acc1.z); u.w = f2bf(acc1.w);
        *(ushort4*)(z + base + FIN) = u;
        u.x = f2bf(acc2.x); u.y = f2bf(acc2.y); u.z = f2bf(acc2.z); u.w = f2bf(acc2.w);
        *(ushort4*)(z + base + 2 * FIN) = u;
        u.x = f2bf(acc3.x); u.y = f2bf(acc3.y); u.z = f2bf(acc3.z); u.w = f2bf(acc3.w);
        *(ushort4*)(z + base + 3 * FIN) = u;
    }
}

// ---------------- esnext fixup: conv epilogue couldn't fold Unext cleanly in
// the record scheme; compute esnext = exp(row . Unext) per node standalone.
// 100K nodes, streaming reads of crec rows just written (L2-hot) — cheap.

template<int FOUT, int ROW_FP8>
__global__ __launch_bounds__(256) void esnext_kernel(
        const char* __restrict__ crec,    // row at +0
        const float* __restrict__ Unext,  // [FOUT,4]
        char* __restrict__ crec_es)       // es written at +32 (same table)
{
    __shared__ float Uloc[FOUT * 4];
    for (int i = threadIdx.x; i < FOUT * 4; i += 256) Uloc[i] = Unext[i];
    __syncthreads();
    int n = blockIdx.x * 256 + threadIdx.x;
    if (n >= N_NODES) return;
    const char* rec = crec + (size_t)n * 64;
    float a0 = 0, a1 = 0, a2 = 0, a3 = 0;
    if (ROW_FP8) {
        #pragma unroll
        for (int j = 0; j < FOUT / 4; j++) {
            unsigned r = *(const unsigned*)(rec + 4 * j);
            #pragma unroll
            for (int t = 0; t < 4; t++) {
                float xv = fp8d((uchar_t)((r >> (8 * t)) & 255));
                int ff = 4 * j + t;
                a0 += xv * Uloc[ff * 4 + 0];
                a1 += xv * Uloc[ff * 4 + 1];
                a2 += xv * Uloc[ff * 4 + 2];
                a3 += xv * Uloc[ff * 4 + 3];
            }
        }
    } else {
        #pragma unroll
        for (int j = 0; j < FOUT / 4; j++) {
            ushort4 r = *(const ushort4*)(rec + 8 * j);
            float x0 = bf2f(r.x), x1 = bf2f(r.y), x2 = bf2f(r.z), x3 = bf2f(r.w);
            int ff = 4 * j;
            a0 += x0 * Uloc[ff * 4 + 0] + x1 * Uloc[(ff + 1) * 4 + 0] +
                  x2 * Uloc[(ff + 2) * 4 + 0] + x3 * Uloc[(ff + 3) * 4 + 0];
            a1 += x0 * Uloc[ff * 4 + 1] + x1 * Uloc[(ff + 1) * 4 + 1] +
                  x2 * Uloc[(ff + 2) * 4 + 1] + x3 * Uloc[(ff + 3) * 4 + 1];
            a2 += x0 * Uloc[ff * 4 + 2] + x1 * Uloc[(ff + 1) * 4 + 2] +
                  x2 * Uloc[(ff + 2) * 4 + 2] + x3 * Uloc[(ff + 3) * 4 + 2];
            a3 += x0 * Uloc[ff * 4 + 3] + x1 * Uloc[(ff + 1) * 4 + 3] +
                  x2 * Uloc[(ff + 2) * 4 + 3] + x3 * Uloc[(ff + 3) * 4 + 3];
        }
    }
    *(float4*)(crec_es + (size_t)n * 64 + 32) =
        make_float4(__expf(a0), __expf(a1), __expf(a2), __expf(a3));
}

// ---------------- post3: z(bf16) -> bf16 h3 (R16-proven standalone) ----------------

template<int FIN, int FOUT>
__global__ __launch_bounds__(256, 4) void post_kernel(
        const ushort_t* __restrict__ z,   // [N, 4*FIN] bf16
        const float* __restrict__ W,      // [FIN, 4*FOUT]
        const float* __restrict__ b,      // [FOUT]
        ushort_t* __restrict__ out_bf)    // [N, FOUT]
{
    constexpr int K   = 4 * FIN;
    constexpr int OL  = FOUT / 4;
    constexpr int NPB = 4 * (256 / OL);
    constexpr int WSZ = FIN * 4 * FOUT;
    __shared__ __align__(16) float Wp[WSZ];
    for (int i = threadIdx.x; i < WSZ; i += 256) {
        int f = i / (4 * FOUT);
        int r = i - f * (4 * FOUT);
        int h = r / FOUT;
        int o = r - h * FOUT;
        Wp[(h * FIN + f) * FOUT + o] = W[i];
    }
    __syncthreads();

    int ol = threadIdx.x % OL;
    int g  = threadIdx.x / OL;
    int n0 = blockIdx.x * NPB + g * 4;

    float4 bv = *(const float4*)(b + 4 * ol);
    float4 acc[4];
    const ushort_t* zr[4];
    #pragma unroll
    for (int j = 0; j < 4; j++) {
        acc[j] = make_float4(0.f, 0.f, 0.f, 0.f);
        int nn = n0 + j; if (nn > N_NODES - 1) nn = N_NODES - 1;
        zr[j] = z + (size_t)nn * K;
    }

    #pragma unroll 2
    for (int kq = 0; kq < K / 4; kq++) {
        float zv[4][4];
        #pragma unroll
        for (int j = 0; j < 4; j++) {
            ushort4 zu = *(const ushort4*)(zr[j] + 4 * kq);
            zv[j][0] = bf2f(zu.x); zv[j][1] = bf2f(zu.y);
            zv[j][2] = bf2f(zu.z); zv[j][3] = bf2f(zu.w);
        }
        #pragma unroll
        for (int jj = 0; jj < 4; jj++) {
            float4 wv = *(const float4*)(Wp + (4 * kq + jj) * FOUT + 4 * ol);
            #pragma unroll
            for (int j = 0; j < 4; j++) {
                float s = zv[j][jj];
                acc[j].x += s * wv.x;
                acc[j].y += s * wv.y;
                acc[j].z += s * wv.z;
                acc[j].w += s * wv.w;
            }
        }
    }

    #pragma unroll
    for (int j = 0; j < 4; j++) {
        int nn = n0 + j;
        if (nn < N_NODES) {
            ushort4 u;
            u.x = f2bf(fmaxf(acc[j].x + bv.x, 0.0f));
            u.y = f2bf(fmaxf(acc[j].y + bv.y, 0.0f));
            u.z = f2bf(fmaxf(acc[j].z + bv.z, 0.0f));
            u.w = f2bf(fmaxf(acc[j].w + bv.w, 0.0f));
            *(ushort4*)(out_bf + (size_t)nn * FOUT + 4 * ol) = u;
        }
    }
}

// ---------------- fused linear tail (bf16 input): 64->32->16->8->4->1 ----------------

__global__ __launch_bounds__(256) void tail_kernel(
        const ushort_t* __restrict__ h,   // [N, 64] bf16
        const float* __restrict__ lw1, const float* __restrict__ lb1,
        const float* __restrict__ lw2, const float* __restrict__ lb2,
        const float* __restrict__ lw3, const float* __restrict__ lb3,
        const float* __restrict__ lw4, const float* __restrict__ lb4,
        const float* __restrict__ lw5, const float* __restrict__ lb5,
        float* __restrict__ out)
{
    __shared__ __align__(16) float w1[64 * 32];
    __shared__ float w2[32 * 16], w3[16 * 8], w4[8 * 4], w5[4];
    __shared__ float B1[32], B2[16], B3[8], B4[4], B5[1];
    for (int i = threadIdx.x; i < 64 * 32; i += blockDim.x) w1[i] = lw1[i];
    for (int i = threadIdx.x; i < 32 * 16; i += blockDim.x) w2[i] = lw2[i];
    for (int i = threadIdx.x; i < 16 * 8;  i += blockDim.x) w3[i] = lw3[i];
    for (int i = threadIdx.x; i < 8 * 4;   i += blockDim.x) w4[i] = lw4[i];
    for (int i = threadIdx.x; i < 4;       i += blockDim.x) w5[i] = lw5[i];
    for (int i = threadIdx.x; i < 32; i += blockDim.x) B1[i] = lb1[i];
    for (int i = threadIdx.x; i < 16; i += blockDim.x) B2[i] = lb2[i];
    for (int i = threadIdx.x; i < 8;  i += blockDim.x) B3[i] = lb3[i];
    for (int i = threadIdx.x; i < 4;  i += blockDim.x) B4[i] = lb4[i];
    if (threadIdx.x == 0) B5[0] = lb5[0];
    __syncthreads();

    int n = blockIdx.x * blockDim.x + threadIdx.x;
    if (n >= N_NODES) return;

    float a[64];
    const uint4* hrow = (const uint4*)(h + (size_t)n * 64);
    #pragma unroll
    for (int j = 0; j < 8; j++) {
        uint4 v = hrow[j];
        unpack2(v.x, a[8 * j + 0], a[8 * j + 1]);
        unpack2(v.y, a[8 * j + 2], a[8 * j + 3]);
        unpack2(v.z, a[8 * j + 4], a[8 * j + 5]);
        unpack2(v.w, a[8 * j + 6], a[8 * j + 7]);
    }

    float t1[32];
    for (int o = 0; o < 32; o++) {
        float acc = B1[o];
        #pragma unroll
        for (int i = 0; i < 64; i++) acc += a[i] * w1[i * 32 + o];
        t1[o] = fmaxf(acc, 0.0f);
    }
    float t2[16];
    for (int o = 0; o < 16; o++) {
        float acc = B2[o];
        #pragma unroll
        for (int i = 0; i < 32; i++) acc += t1[i] * w2[i * 16 + o];
        t2[o] = fmaxf(acc, 0.0f);
    }
    float t3[8];
    for (int o = 0; o < 8; o++) {
        float acc = B3[o];
        #pragma unroll
        for (int i = 0; i < 16; i++) acc += t2[i] * w3[i * 8 + o];
        t3[o] = fmaxf(acc, 0.0f);
    }
    float t4[4];
    for (int o = 0; o < 4; o++) {
        float acc = B4[o];
        #pragma unroll
        for (int i = 0; i < 8; i++) acc += t3[i] * w4[i * 4 + o];
        t4[o] = fmaxf(acc, 0.0f);
    }
    float zf = B5[0];
    #pragma unroll
    for (int i = 0; i < 4; i++) zf += t4[i] * w5[i];
    out[n] = 1.0f / (1.0f + expf(-zf));
}

// ---------------- host launch ----------------

extern "C" void kernel_launch(void* const* d_in, const int* in_sizes, int n_in,
                              void* d_out, int out_size, void* d_ws, size_t ws_size,
                              hipStream_t stream) {
    const float* x   = (const float*)d_in[0];
    const int*   ei  = (const int*)d_in[1];
    const int*   src = ei;
    const int*   dst = ei + N_EDGES;
    const float* U1 = (const float*)d_in[2];  const float* c1 = (const float*)d_in[3];
    const float* W1 = (const float*)d_in[4];  const float* b1 = (const float*)d_in[5];
    const float* U2 = (const float*)d_in[6];  const float* c2 = (const float*)d_in[7];
    const float* W2 = (const float*)d_in[8];  const float* b2 = (const float*)d_in[9];
    const float* U3 = (const float*)d_in[10]; const float* c3 = (const float*)d_in[11];
    const float* W3 = (const float*)d_in[12]; const float* b3 = (const float*)d_in[13];
    const float* lw1 = (const float*)d_in[14]; const float* lb1 = (const float*)d_in[15];
    const float* lw2 = (const float*)d_in[16]; const float* lb2 = (const float*)d_in[17];
    const float* lw3 = (const float*)d_in[18]; const float* lb3 = (const float*)d_in[19];
    const float* lw4 = (const float*)d_in[20]; const float* lb4 = (const float*)d_in[21];
    const float* lw5 = (const float*)d_in[22]; const float* lb5 = (const float*)d_in[23];

    char* ws = (char*)d_ws;
    size_t off = 0;
    auto alloc = [&](size_t bytes) -> void* {
        void* ptr = (void*)(ws + off);
        off += (bytes + 255) & ~(size_t)255;
        return ptr;
    };
    int*      hist_rows     = (int*)alloc((size_t)NCHUNK * NBKT * 4);
    int*      bucket_cnt    = (int*)alloc((size_t)(NBKT + 1) * 4);
    int*      bucket_base   = (int*)alloc((size_t)(NBKT + 1) * 4);
    int*      bucket_cursor = (int*)alloc((size_t)NBKT * 4);
    int*      csr_tmp       = (int*)alloc((size_t)N_EDGES * 4);
    int*      rowptr        = (int*)alloc(((size_t)N_NODES + 1) * 4);
    int*      csr_src       = (int*)alloc((size_t)N_EDGES * 4);
    char*     crec1         = (char*)alloc((size_t)N_NODES * 64);
    char*     crec2         = (char*)alloc((size_t)N_NODES * 64);
    char*     crec3         = (char*)alloc((size_t)N_NODES * 64);
    ushort_t* z             = (ushort_t*)alloc((size_t)N_NODES * 128 * 2);
    ushort_t* h3bf          = (ushort_t*)alloc((size_t)N_NODES * 64 * 2);
    (void)ws_size;

    const int B = 256;

    // ---- CSR build + crec1 (x row + es1) ----
    bhist_pcast_kernel<<<NCHUNK + GN + 1, B, 0, stream>>>(dst, hist_rows, x, U1,
                                                          crec1, bucket_cnt);
    ksum_kernel<<<NRB, B, 0, stream>>>(hist_rows, bucket_cnt);
    bscan_kernel<<<1, 512, 0, stream>>>(bucket_cnt, bucket_base, bucket_cursor);
    partition_kernel<<<NCHUNK, B, 0, stream>>>(src, dst, bucket_cursor, csr_tmp);
    bucket_build_kernel<<<NBKT, B, 0, stream>>>(bucket_base, csr_tmp, rowptr, csr_src);

    const int ZG16 = (N_NODES + 63) / 64;    // NPB=64
    const int ZG32 = (N_NODES + 31) / 32;    // NPB=32
    const int NPB3 = 4 * (256 / (64 / 4));   // 64

    // ---- conv1: crec1 -> crec2 row (bf16 h1); then es2 fixup ----
    conv_fused_kernel<16, 16, 0><<<ZG16, B, 0, stream>>>(
        rowptr, csr_src, crec1, c1, W1, b1, crec2);
    esnext_kernel<16, 0><<<GN, B, 0, stream>>>(crec2, U2, crec2);

    // ---- conv2: crec2 -> crec3 row (fp8 h2); then es3 fixup ----
    conv_fused_kernel<16, 32, 1><<<ZG16, B, 0, stream>>>(
        rowptr, csr_src, crec2, c2, W2, b2, crec3);
    esnext_kernel<32, 1><<<GN, B, 0, stream>>>(crec3, U3, crec3);

    // ---- conv3: fp8 gather -> z(bf16); post3 -> bf16 h3; tail -> sigmoid ----
    zgather_kernel<32><<<ZG32, B, 0, stream>>>(rowptr, csr_src, crec3, c3, z);
    post_kernel<32, 64><<<(N_NODES + NPB3 - 1) / NPB3, B, 0, stream>>>(z, W3, b3, h3bf);
    tail_kernel<<<GN, B, 0, stream>>>(h3bf, lw1, lb1, lw2, lb2, lw3, lb3,
                                      lw4, lb4, lw5, lb5, (float*)d_out);
}

// Round 8
// 320.252 us; speedup vs baseline: 1.0887x; 1.0887x over previous
//
#include <hip/hip_runtime.h>
#include <math.h>

#define N_NODES 100000
#define N_EDGES 1600000
#define HEADS 4
#define NBKT ((N_NODES + 255) / 256)
#define CHUNK_E 4096
#define NCHUNK ((N_EDGES + CHUNK_E - 1) / CHUNK_E)
#define GN ((N_NODES + 255) / 256)
#define SUM_ROWS 16
#define NRB ((NCHUNK + SUM_ROWS - 1) / SUM_ROWS)

typedef unsigned short ushort_t;
typedef unsigned char  uchar_t;

__device__ __forceinline__ ushort_t f2bf(float x) {
    unsigned u = __float_as_uint(x);
    u += 0x7FFF + ((u >> 16) & 1);
    return (ushort_t)(u >> 16);
}
__device__ __forceinline__ float bf2f(ushort_t v) {
    return __uint_as_float(((unsigned)v) << 16);
}
__device__ __forceinline__ void unpack2(unsigned u, float& lo, float& hi) {
    lo = __uint_as_float(u << 16);
    hi = __uint_as_float(u & 0xffff0000u);
}
// unsigned e5m3 fp8 (ReLU outputs only)
__device__ __forceinline__ uchar_t f2fp8(float x) {
    if (x <= 0.0f) return 0;
    unsigned u = __float_as_uint(x) + (1u << 19);
    int e = (int)(u >> 23) - 127 + 15;
    if (e <= 0) return 0;
    if (e > 31) return (uchar_t)255;
    return (uchar_t)((e << 3) | ((u >> 20) & 7));
}
__device__ __forceinline__ float fp8d(uchar_t b) {
    unsigned v = (((unsigned)(b >> 3) + 112u) << 23) | ((unsigned)(b & 7) << 20);
    return (b == 0) ? 0.0f : __uint_as_float(v);
}

// ---------------- K1: per-chunk histogram rows + es1/x->bf16 + bucket_cnt zero ----
// R21 (best measured, 324us total): p buffer stores es[h] = exp(p[h]) per node
// (softmax exp hoisted out of the per-edge loops).

__global__ __launch_bounds__(256) void bhist_pcast_kernel(
        const int* __restrict__ dst, int* __restrict__ hist_rows,
        const float* __restrict__ x, const float* __restrict__ U,
        float* __restrict__ p, ushort_t* __restrict__ xbf,
        int* __restrict__ bucket_cnt)
{
    __shared__ int h[NBKT];
    if (blockIdx.x < NCHUNK) {
        for (int i = threadIdx.x; i < NBKT; i += 256) h[i] = 0;
        __syncthreads();
        int base = blockIdx.x * CHUNK_E;
        #pragma unroll
        for (int j = 0; j < CHUNK_E / 256; j++) {
            int e = base + j * 256 + threadIdx.x;
            if (e < N_EDGES) atomicAdd(&h[dst[e] >> 8], 1);
        }
        __syncthreads();
        for (int i = threadIdx.x; i < NBKT; i += 256)
            hist_rows[(size_t)blockIdx.x * NBKT + i] = h[i];
    } else if (blockIdx.x < NCHUNK + GN) {
        int n = (blockIdx.x - NCHUNK) * 256 + threadIdx.x;
        if (n >= N_NODES) return;
        float a0 = 0, a1 = 0, a2 = 0, a3 = 0;
        const float* hr = x + (size_t)n * 16;
        float xv[16];
        #pragma unroll
        for (int f = 0; f < 16; f++) {
            xv[f] = hr[f];
            a0 += xv[f] * U[f * 4 + 0];
            a1 += xv[f] * U[f * 4 + 1];
            a2 += xv[f] * U[f * 4 + 2];
            a3 += xv[f] * U[f * 4 + 3];
        }
        *(float4*)(p + (size_t)n * 4) =
            make_float4(__expf(a0), __expf(a1), __expf(a2), __expf(a3));
        #pragma unroll
        for (int j = 0; j < 4; j++) {
            ushort4 u;
            u.x = f2bf(xv[4 * j + 0]); u.y = f2bf(xv[4 * j + 1]);
            u.z = f2bf(xv[4 * j + 2]); u.w = f2bf(xv[4 * j + 3]);
            *(ushort4*)(xbf + (size_t)n * 16 + 4 * j) = u;
        }
    } else {
        for (int i = threadIdx.x; i < NBKT; i += 256) bucket_cnt[i] = 0;
    }
}

// ---------------- K2a: parallel column-sum ----

__global__ __launch_bounds__(256) void ksum_kernel(const int* __restrict__ hist_rows,
                                                   int* __restrict__ bucket_cnt) {
    int r0 = blockIdx.x * SUM_ROWS;
    int r1 = min(r0 + SUM_ROWS, NCHUNK);
    for (int i = threadIdx.x; i < NBKT; i += 256) {
        int v = 0;
        for (int r = r0; r < r1; r++) v += hist_rows[(size_t)r * NBKT + i];
        if (v) atomicAdd(&bucket_cnt[i], v);
    }
}

// ---------------- K2b: exclusive scan -> base + cursor ----

__global__ __launch_bounds__(512) void bscan_kernel(const int* __restrict__ bucket_cnt,
                                                    int* __restrict__ bucket_base,
                                                    int* __restrict__ bucket_cursor) {
    __shared__ int tmp[512];
    int i = threadIdx.x;
    int v = (i < NBKT) ? bucket_cnt[i] : 0;
    tmp[i] = v;
    __syncthreads();
    for (int off = 1; off < 512; off <<= 1) {
        int t = (i >= off) ? tmp[i - off] : 0;
        __syncthreads();
        tmp[i] += t;
        __syncthreads();
    }
    int excl = tmp[i] - v;
    if (i < NBKT) { bucket_base[i] = excl; bucket_cursor[i] = excl; }
    if (i == NBKT) bucket_base[NBKT] = N_EDGES;
}

// ---------------- K3: partition into coarse buckets; packed = (dst&255)<<20 | src ----

__global__ __launch_bounds__(256) void partition_kernel(const int* __restrict__ src,
                                                        const int* __restrict__ dst,
                                                        int* __restrict__ bucket_cursor,
                                                        int* __restrict__ csr_tmp) {
    constexpr int EPT = CHUNK_E / 256;
    __shared__ int h[NBKT];
    __shared__ int gbase[NBKT];
    __shared__ int rcnt[NBKT];
    for (int i = threadIdx.x; i < NBKT; i += 256) { h[i] = 0; rcnt[i] = 0; }
    __syncthreads();
    int base = blockIdx.x * CHUNK_E;
    int d[EPT], s[EPT];
    #pragma unroll
    for (int j = 0; j < EPT; j++) {
        int e = base + j * 256 + threadIdx.x;
        d[j] = (e < N_EDGES) ? dst[e] : -1;
        s[j] = (e < N_EDGES) ? src[e] : 0;
        if (d[j] >= 0) atomicAdd(&h[d[j] >> 8], 1);
    }
    __syncthreads();
    for (int i = threadIdx.x; i < NBKT; i += 256)
        if (h[i]) gbase[i] = atomicAdd(&bucket_cursor[i], h[i]);
    __syncthreads();
    #pragma unroll
    for (int j = 0; j < EPT; j++) {
        if (d[j] >= 0) {
            int b = d[j] >> 8;
            int r = atomicAdd(&rcnt[b], 1);
            csr_tmp[gbase[b] + r] = ((d[j] & 255) << 20) | s[j];
        }
    }
}

// ---------------- K4: per-bucket build; csr_src keeps dlow packed ----

__global__ __launch_bounds__(256) void bucket_build_kernel(const int* __restrict__ bucket_base,
                                                           const int* __restrict__ csr_tmp,
                                                           int* __restrict__ rowptr,
                                                           int* __restrict__ csr_src) {
    __shared__ int cnt[256];
    __shared__ int tscan[256];
    __shared__ int exc[256];
    __shared__ int stage[8192];
    int b = blockIdx.x;
    int rbeg = bucket_base[b], rend = bucket_base[b + 1];
    int sz = rend - rbeg;
    int tid = threadIdx.x;

    cnt[tid] = 0;
    __syncthreads();
    for (int k = rbeg + tid; k < rend; k += 256) atomicAdd(&cnt[csr_tmp[k] >> 20], 1);
    __syncthreads();
    int v = cnt[tid];
    tscan[tid] = v;
    __syncthreads();
    for (int off = 1; off < 256; off <<= 1) {
        int t = (tid >= off) ? tscan[tid - off] : 0;
        __syncthreads();
        tscan[tid] += t;
        __syncthreads();
    }
    int ex = tscan[tid] - v;
    int node = b * 256 + tid;
    if (node < N_NODES) rowptr[node] = rbeg + ex;
    if (b == 0 && tid == 0) rowptr[N_NODES] = N_EDGES;
    exc[tid] = ex;
    cnt[tid] = 0;
    __syncthreads();

    if (sz <= 8192) {
        for (int k = rbeg + tid; k < rend; k += 256) {
            int pk = csr_tmp[k];
            int dl = pk >> 20;
            int r  = atomicAdd(&cnt[dl], 1);
            stage[exc[dl] + r] = pk;
        }
        __syncthreads();
        for (int i = tid; i < sz; i += 256) csr_src[rbeg + i] = stage[i];
    } else {
        for (int k = rbeg + tid; k < rend; k += 256) {
            int pk = csr_tmp[k];
            int dl = pk >> 20;
            int r  = atomicAdd(&cnt[dl], 1);
            csr_src[rbeg + exc[dl] + r] = pk;
        }
    }
}

// ---------------- fused conv (conv1/conv2): R21 = proven R0 two-phase
// structure + ES/ED softmax refactor.  es[] holds exp(p) per node; pds holds
// ed[h] = exp(c_h)/es_d[h].  q-phase per edge: gather es[s] (16B) then
// 4 mul + 3 add + 1 div + 4 mul -- no exp, no max (ranges bounded, fp32-safe).
// exp moved to per-node epilogue (esnext).
// Floor evidence (R18-R22): conv sits at a random-gather latency floor
// (~2 L2-hit lines/edge); VALU, request-count, address-count, occupancy,
// and line-merging levers are all measured null-or-negative.

template<int FIN, int FOUT, int OUT_FP8>
__global__ __launch_bounds__(256) void conv_fused_kernel(
        const int* __restrict__ rowptr, const int* __restrict__ csr_src,
        const float* __restrict__ es, const float* __restrict__ cvec,
        const ushort_t* __restrict__ hprev,   // [N, FIN] bf16
        const float* __restrict__ W,          // [FIN, 4*FOUT]
        const float* __restrict__ b,          // [FOUT]
        ushort_t* __restrict__ out_bf,        // [N, FOUT] (OUT_FP8==0)
        uchar_t* __restrict__ out_f8,         // [N, FOUT] (OUT_FP8==1)
        const float* __restrict__ Unext,      // [FOUT,4]
        float* __restrict__ esnext)           // [N,4] exp(pnext)
{
    constexpr int LPN   = FIN / 4;            // 4
    constexpr int NPB   = 256 / LPN;          // 64
    constexpr int CHUNK = 1024;
    constexpr int K     = 4 * FIN;            // 64
    constexpr int ZK    = K + 4;
    constexpr int HS    = FOUT + 1;
    constexpr int WSZ   = K * FOUT;
    constexpr int UNION_A = CHUNK * 16 + CHUNK * 4;
    constexpr int UNION_B = NPB * ZK * 4 + NPB * HS * 4;
    constexpr int UNION   = UNION_A > UNION_B ? UNION_A : UNION_B;

    __shared__ int    sbeg[NPB + 1];
    __shared__ __align__(16) float4 pds[NPB];    // ed per local node
    __shared__ __align__(16) float  Ws[WSZ];
    __shared__ float  Uloc[FOUT * 4];
    __shared__ __align__(16) char ubuf[UNION];
    float4* qs    = (float4*)ubuf;
    int*    ssrc  = (int*)(ubuf + CHUNK * 16);
    float*  ztile = (float*)ubuf;
    float*  hout  = (float*)(ubuf + NPB * ZK * 4);

    int tid  = threadIdx.x;
    int nloc = tid / LPN;
    int fl   = (tid - nloc * LPN) * 4;
    int n0   = blockIdx.x * NPB;
    int dbase = n0 & 255;

    float ec0 = __expf(cvec[0]), ec1 = __expf(cvec[1]);
    float ec2 = __expf(cvec[2]), ec3 = __expf(cvec[3]);

    for (int i = tid; i <= NPB; i += 256) {
        int idx = n0 + i;
        sbeg[i] = rowptr[idx > N_NODES ? N_NODES : idx];
    }
    for (int i = tid; i < NPB; i += 256) {
        int idx = n0 + i;
        float4 e = *(const float4*)(es + (size_t)(idx < N_NODES ? idx : N_NODES - 1) * 4);
        pds[i] = make_float4(ec0 / e.x, ec1 / e.y, ec2 / e.z, ec3 / e.w);
    }
    for (int i = tid; i < WSZ; i += 256) {
        int f = i / (4 * FOUT);
        int r = i - f * (4 * FOUT);
        int h = r / FOUT;
        int o = r - h * FOUT;
        Ws[(h * FIN + f) * FOUT + o] = W[i];
    }
    for (int i = tid; i < FOUT * 4; i += 256) Uloc[i] = Unext[i];
    __syncthreads();

    int BB = sbeg[0], BE = sbeg[NPB];
    int beg = sbeg[nloc], end = sbeg[nloc + 1];

    float4 acc0 = make_float4(0, 0, 0, 0), acc1 = acc0, acc2 = acc0, acc3 = acc0;

    for (int cbase = BB; cbase < BE; cbase += CHUNK) {
        int cend = min(cbase + CHUNK, BE);
        __syncthreads();
        for (int k = cbase + tid; k < cend; k += 256) {
            int pk = csr_src[k];
            int s  = pk & ((1 << 20) - 1);
            int nl = (pk >> 20) - dbase;
            float4 e  = *(const float4*)(es + (size_t)s * 4);
            float4 ed = pds[nl];
            float w0 = e.x * ed.x;
            float w1 = e.y * ed.y;
            float w2 = e.z * ed.z;
            float w3 = e.w * ed.w;
            float deg = (float)(sbeg[nl + 1] - sbeg[nl]);
            float inv = 1.0f / (fmaxf(deg, 1.0f) * (w0 + w1 + w2 + w3));
            qs[k - cbase]   = make_float4(w0 * inv, w1 * inv, w2 * inv, w3 * inv);
            ssrc[k - cbase] = s;
        }
        __syncthreads();
        int kb = (beg > cbase ? beg : cbase) - cbase;
        int ke = (end < cend ? end : cend) - cbase;
        int k = kb;
        for (; k + 4 <= ke; k += 4) {
            uint2 r[4];
            #pragma unroll
            for (int j = 0; j < 4; j++)
                r[j] = *(const uint2*)(hprev + (size_t)ssrc[k + j] * FIN + fl);
            float xv[4][4];
            #pragma unroll
            for (int j = 0; j < 4; j++) {
                unpack2(r[j].x, xv[j][0], xv[j][1]);
                unpack2(r[j].y, xv[j][2], xv[j][3]);
            }
            #pragma unroll
            for (int j = 0; j < 4; j++) {
                float4 q = qs[k + j];
                acc0.x += q.x * xv[j][0]; acc0.y += q.x * xv[j][1];
                acc0.z += q.x * xv[j][2]; acc0.w += q.x * xv[j][3];
                acc1.x += q.y * xv[j][0]; acc1.y += q.y * xv[j][1];
                acc1.z += q.y * xv[j][2]; acc1.w += q.y * xv[j][3];
                acc2.x += q.z * xv[j][0]; acc2.y += q.z * xv[j][1];
                acc2.z += q.z * xv[j][2]; acc2.w += q.z * xv[j][3];
                acc3.x += q.w * xv[j][0]; acc3.y += q.w * xv[j][1];
                acc3.z += q.w * xv[j][2]; acc3.w += q.w * xv[j][3];
            }
        }
        for (; k < ke; k++) {
            float x0, x1, x2, x3;
            uint2 r = *(const uint2*)(hprev + (size_t)ssrc[k] * FIN + fl);
            unpack2(r.x, x0, x1);
            unpack2(r.y, x2, x3);
            float4 q = qs[k];
            acc0.x += q.x * x0; acc0.y += q.x * x1; acc0.z += q.x * x2; acc0.w += q.x * x3;
            acc1.x += q.y * x0; acc1.y += q.y * x1; acc1.z += q.y * x2; acc1.w += q.y * x3;
            acc2.x += q.z * x0; acc2.y += q.z * x1; acc2.z += q.z * x2; acc2.w += q.z * x3;
            acc3.x += q.w * x0; acc3.y += q.w * x1; acc3.z += q.w * x2; acc3.w += q.w * x3;
        }
    }

    __syncthreads();
    {
        float* zr = ztile + nloc * ZK;
        *(float4*)(zr + 0 * FIN + fl) = acc0;
        *(float4*)(zr + 1 * FIN + fl) = acc1;
        *(float4*)(zr + 2 * FIN + fl) = acc2;
        *(float4*)(zr + 3 * FIN + fl) = acc3;
    }
    __syncthreads();

    constexpr int OQ  = FOUT / 4;
    constexpr int QPT = (NPB * OQ) / 256;
    #pragma unroll
    for (int rq = 0; rq < QPT; rq++) {
        int idx = tid + 256 * rq;
        int j   = idx / OQ;
        int o4  = idx - j * OQ;
        float4 acc = *(const float4*)(b + 4 * o4);
        const float* zr = ztile + j * ZK;
        #pragma unroll 4
        for (int kq = 0; kq < K / 4; kq++) {
            float4 zt = *(const float4*)(zr + 4 * kq);
            #pragma unroll
            for (int jj = 0; jj < 4; jj++) {
                float4 wv = *(const float4*)(Ws + (4 * kq + jj) * FOUT + 4 * o4);
                float s = (&zt.x)[jj];
                acc.x += s * wv.x;
                acc.y += s * wv.y;
                acc.z += s * wv.z;
                acc.w += s * wv.w;
            }
        }
        acc.x = fmaxf(acc.x, 0.0f);
        acc.y = fmaxf(acc.y, 0.0f);
        acc.z = fmaxf(acc.z, 0.0f);
        acc.w = fmaxf(acc.w, 0.0f);
        float* hr = hout + j * HS + 4 * o4;
        hr[0] = acc.x; hr[1] = acc.y; hr[2] = acc.z; hr[3] = acc.w;
        int nn = n0 + j;
        if (nn < N_NODES) {
            if (OUT_FP8) {
                unsigned pk = (unsigned)f2fp8(acc.x) | ((unsigned)f2fp8(acc.y) << 8) |
                              ((unsigned)f2fp8(acc.z) << 16) | ((unsigned)f2fp8(acc.w) << 24);
                *(unsigned*)(out_f8 + (size_t)nn * FOUT + 4 * o4) = pk;
            } else {
                ushort4 u;
                u.x = f2bf(acc.x); u.y = f2bf(acc.y); u.z = f2bf(acc.z); u.w = f2bf(acc.w);
                *(ushort4*)(out_bf + (size_t)nn * FOUT + 4 * o4) = u;
            }
        }
    }

    __syncthreads();
    if (tid < NPB) {
        int nn = n0 + tid;
        if (nn < N_NODES) {
            float a0 = 0, a1 = 0, a2 = 0, a3 = 0;
            const float* hr = hout + tid * HS;
            #pragma unroll
            for (int ff = 0; ff < FOUT; ff++) {
                float xv = hr[ff];
                a0 += xv * Uloc[ff * 4 + 0];
                a1 += xv * Uloc[ff * 4 + 1];
                a2 += xv * Uloc[ff * 4 + 2];
                a3 += xv * Uloc[ff * 4 + 3];
            }
            *(float4*)(esnext + (size_t)nn * 4) =
                make_float4(__expf(a0), __expf(a1), __expf(a2), __expf(a3));
        }
    }
}

// ---------------- zgather v5 (conv3, fp8 in), z out bf16; R21 ES/ED q-phase ----

template<int FIN>
__global__ __launch_bounds__(256) void zgather_kernel(
        const int* __restrict__ rowptr, const int* __restrict__ csr_src,
        const float* __restrict__ es, const float* __restrict__ cvec,
        const uchar_t* __restrict__ hf8,  // [N, FIN] fp8
        ushort_t* __restrict__ z)         // [N, 4*FIN] bf16
{
    constexpr int LPN   = FIN / 4;
    constexpr int NPB   = 256 / LPN;
    constexpr int CHUNK = 1024;
    __shared__ int    sbeg[NPB + 1];
    __shared__ __align__(16) float4 pds[NPB];
    __shared__ __align__(16) float4 qs[CHUNK];
    __shared__ int    ssrc[CHUNK];

    int tid  = threadIdx.x;
    int nloc = tid / LPN;
    int fl   = (tid - nloc * LPN) * 4;
    int n0   = blockIdx.x * NPB;
    int n    = n0 + nloc;
    int dbase = n0 & 255;

    float ec0 = __expf(cvec[0]), ec1 = __expf(cvec[1]);
    float ec2 = __expf(cvec[2]), ec3 = __expf(cvec[3]);

    for (int i = tid; i <= NPB; i += 256) {
        int idx = n0 + i;
        sbeg[i] = rowptr[idx > N_NODES ? N_NODES : idx];
    }
    for (int i = tid; i < NPB; i += 256) {
        int idx = n0 + i;
        float4 e = *(const float4*)(es + (size_t)(idx < N_NODES ? idx : N_NODES - 1) * 4);
        pds[i] = make_float4(ec0 / e.x, ec1 / e.y, ec2 / e.z, ec3 / e.w);
    }
    __syncthreads();

    int BB = sbeg[0], BE = sbeg[NPB];
    int beg = sbeg[nloc], end = sbeg[nloc + 1];

    float4 acc0 = make_float4(0, 0, 0, 0), acc1 = acc0, acc2 = acc0, acc3 = acc0;

    for (int cbase = BB; cbase < BE; cbase += CHUNK) {
        int cend = min(cbase + CHUNK, BE);
        __syncthreads();
        for (int k = cbase + tid; k < cend; k += 256) {
            int pk = csr_src[k];
            int s  = pk & ((1 << 20) - 1);
            int nl = (pk >> 20) - dbase;
            float4 e  = *(const float4*)(es + (size_t)s * 4);
            float4 ed = pds[nl];
            float w0 = e.x * ed.x;
            float w1 = e.y * ed.y;
            float w2 = e.z * ed.z;
            float w3 = e.w * ed.w;
            float deg = (float)(sbeg[nl + 1] - sbeg[nl]);
            float inv = 1.0f / (fmaxf(deg, 1.0f) * (w0 + w1 + w2 + w3));
            qs[k - cbase]   = make_float4(w0 * inv, w1 * inv, w2 * inv, w3 * inv);
            ssrc[k - cbase] = s;
        }
        __syncthreads();
        int kb = (beg > cbase ? beg : cbase) - cbase;
        int ke = (end < cend ? end : cend) - cbase;
        int k = kb;
        for (; k + 4 <= ke; k += 4) {
            unsigned r[4];
            #pragma unroll
            for (int j = 0; j < 4; j++)
                r[j] = *(const unsigned*)(hf8 + (size_t)ssrc[k + j] * FIN + fl);
            float xv[4][4];
            #pragma unroll
            for (int j = 0; j < 4; j++) {
                xv[j][0] = fp8d((uchar_t)(r[j] & 255));
                xv[j][1] = fp8d((uchar_t)((r[j] >> 8) & 255));
                xv[j][2] = fp8d((uchar_t)((r[j] >> 16) & 255));
                xv[j][3] = fp8d((uchar_t)(r[j] >> 24));
            }
            #pragma unroll
            for (int j = 0; j < 4; j++) {
                float4 q = qs[k + j];
                acc0.x += q.x * xv[j][0]; acc0.y += q.x * xv[j][1];
                acc0.z += q.x * xv[j][2]; acc0.w += q.x * xv[j][3];
                acc1.x += q.y * xv[j][0]; acc1.y += q.y * xv[j][1];
                acc1.z += q.y * xv[j][2]; acc1.w += q.y * xv[j][3];
                acc2.x += q.z * xv[j][0]; acc2.y += q.z * xv[j][1];
                acc2.z += q.z * xv[j][2]; acc2.w += q.z * xv[j][3];
                acc3.x += q.w * xv[j][0]; acc3.y += q.w * xv[j][1];
                acc3.z += q.w * xv[j][2]; acc3.w += q.w * xv[j][3];
            }
        }
        for (; k < ke; k++) {
            unsigned r = *(const unsigned*)(hf8 + (size_t)ssrc[k] * FIN + fl);
            float x0 = fp8d((uchar_t)(r & 255));
            float x1 = fp8d((uchar_t)((r >> 8) & 255));
            float x2 = fp8d((uchar_t)((r >> 16) & 255));
            float x3 = fp8d((uchar_t)(r >> 24));
            float4 q = qs[k];
            acc0.x += q.x * x0; acc0.y += q.x * x1; acc0.z += q.x * x2; acc0.w += q.x * x3;
            acc1.x += q.y * x0; acc1.y += q.y * x1; acc1.z += q.y * x2; acc1.w += q.y * x3;
            acc2.x += q.z * x0; acc2.y += q.z * x1; acc2.z += q.z * x2; acc2.w += q.z * x3;
            acc3.x += q.w * x0; acc3.y += q.w * x1; acc3.z += q.w * x2; acc3.w += q.w * x3;
        }
    }

    if (n < N_NODES) {
        size_t base = (size_t)n * (4 * FIN) + fl;
        ushort4 u;
        u.x = f2bf(acc0.x); u.y = f2bf(acc0.y); u.z = f2bf(acc0.z); u.w = f2bf(acc0.w);
        *(ushort4*)(z + base) = u;
        u.x = f2bf(acc1.x); u.y = f2bf(acc1.y); u.z = f2bf(acc1.z); u.w = f2bf(acc1.w);
        *(ushort4*)(z + base + FIN) = u;
        u.x = f2bf(acc2.x); u.y = f2bf(acc2.y); u.z = f2bf(acc2.z); u.w = f2bf(acc2.w);
        *(ushort4*)(z + base + 2 * FIN) = u;
        u.x = f2bf(acc3.x); u.y = f2bf(acc3.y); u.z = f2bf(acc3.z); u.w = f2bf(acc3.w);
        *(ushort4*)(z + base + 3 * FIN) = u;
    }
}

// ---------------- post3: z(bf16) -> bf16 h3 (R16-proven standalone) ----------------

template<int FIN, int FOUT>
__global__ __launch_bounds__(256, 4) void post_kernel(
        const ushort_t* __restrict__ z,   // [N, 4*FIN] bf16
        const float* __restrict__ W,      // [FIN, 4*FOUT]
        const float* __restrict__ b,      // [FOUT]
        ushort_t* __restrict__ out_bf)    // [N, FOUT]
{
    constexpr int K   = 4 * FIN;
    constexpr int OL  = FOUT / 4;
    constexpr int NPB = 4 * (256 / OL);
    constexpr int WSZ = FIN * 4 * FOUT;
    __shared__ __align__(16) float Wp[WSZ];
    for (int i = threadIdx.x; i < WSZ; i += 256) {
        int f = i / (4 * FOUT);
        int r = i - f * (4 * FOUT);
        int h = r / FOUT;
        int o = r - h * FOUT;
        Wp[(h * FIN + f) * FOUT + o] = W[i];
    }
    __syncthreads();

    int ol = threadIdx.x % OL;
    int g  = threadIdx.x / OL;
    int n0 = blockIdx.x * NPB + g * 4;

    float4 bv = *(const float4*)(b + 4 * ol);
    float4 acc[4];
    const ushort_t* zr[4];
    #pragma unroll
    for (int j = 0; j < 4; j++) {
        acc[j] = make_float4(0.f, 0.f, 0.f, 0.f);
        int nn = n0 + j; if (nn > N_NODES - 1) nn = N_NODES - 1;
        zr[j] = z + (size_t)nn * K;
    }

    #pragma unroll 2
    for (int kq = 0; kq < K / 4; kq++) {
        float zv[4][4];
        #pragma unroll
        for (int j = 0; j < 4; j++) {
            ushort4 zu = *(const ushort4*)(zr[j] + 4 * kq);
            zv[j][0] = bf2f(zu.x); zv[j][1] = bf2f(zu.y);
            zv[j][2] = bf2f(zu.z); zv[j][3] = bf2f(zu.w);
        }
        #pragma unroll
        for (int jj = 0; jj < 4; jj++) {
            float4 wv = *(const float4*)(Wp + (4 * kq + jj) * FOUT + 4 * ol);
            #pragma unroll
            for (int j = 0; j < 4; j++) {
                float s = zv[j][jj];
                acc[j].x += s * wv.x;
                acc[j].y += s * wv.y;
                acc[j].z += s * wv.z;
                acc[j].w += s * wv.w;
            }
        }
    }

    #pragma unroll
    for (int j = 0; j < 4; j++) {
        int nn = n0 + j;
        if (nn < N_NODES) {
            ushort4 u;
            u.x = f2bf(fmaxf(acc[j].x + bv.x, 0.0f));
            u.y = f2bf(fmaxf(acc[j].y + bv.y, 0.0f));
            u.z = f2bf(fmaxf(acc[j].z + bv.z, 0.0f));
            u.w = f2bf(fmaxf(acc[j].w + bv.w, 0.0f));
            *(ushort4*)(out_bf + (size_t)nn * FOUT + 4 * ol) = u;
        }
    }
}

// ---------------- fused linear tail (bf16 input): 64->32->16->8->4->1 ----------------

__global__ __launch_bounds__(256) void tail_kernel(
        const ushort_t* __restrict__ h,   // [N, 64] bf16
        const float* __restrict__ lw1, const float* __restrict__ lb1,
        const float* __restrict__ lw2, const float* __restrict__ lb2,
        const float* __restrict__ lw3, const float* __restrict__ lb3,
        const float* __restrict__ lw4, const float* __restrict__ lb4,
        const float* __restrict__ lw5, const float* __restrict__ lb5,
        float* __restrict__ out)
{
    __shared__ __align__(16) float w1[64 * 32];
    __shared__ float w2[32 * 16], w3[16 * 8], w4[8 * 4], w5[4];
    __shared__ float B1[32], B2[16], B3[8], B4[4], B5[1];
    for (int i = threadIdx.x; i < 64 * 32; i += blockDim.x) w1[i] = lw1[i];
    for (int i = threadIdx.x; i < 32 * 16; i += blockDim.x) w2[i] = lw2[i];
    for (int i = threadIdx.x; i < 16 * 8;  i += blockDim.x) w3[i] = lw3[i];
    for (int i = threadIdx.x; i < 8 * 4;   i += blockDim.x) w4[i] = lw4[i];
    for (int i = threadIdx.x; i < 4;       i += blockDim.x) w5[i] = lw5[i];
    for (int i = threadIdx.x; i < 32; i += blockDim.x) B1[i] = lb1[i];
    for (int i = threadIdx.x; i < 16; i += blockDim.x) B2[i] = lb2[i];
    for (int i = threadIdx.x; i < 8;  i += blockDim.x) B3[i] = lb3[i];
    for (int i = threadIdx.x; i < 4;  i += blockDim.x) B4[i] = lb4[i];
    if (threadIdx.x == 0) B5[0] = lb5[0];
    __syncthreads();

    int n = blockIdx.x * blockDim.x + threadIdx.x;
    if (n >= N_NODES) return;

    float a[64];
    const uint4* hrow = (const uint4*)(h + (size_t)n * 64);
    #pragma unroll
    for (int j = 0; j < 8; j++) {
        uint4 v = hrow[j];
        unpack2(v.x, a[8 * j + 0], a[8 * j + 1]);
        unpack2(v.y, a[8 * j + 2], a[8 * j + 3]);
        unpack2(v.z, a[8 * j + 4], a[8 * j + 5]);
        unpack2(v.w, a[8 * j + 6], a[8 * j + 7]);
    }

    float t1[32];
    for (int o = 0; o < 32; o++) {
        float acc = B1[o];
        #pragma unroll
        for (int i = 0; i < 64; i++) acc += a[i] * w1[i * 32 + o];
        t1[o] = fmaxf(acc, 0.0f);
    }
    float t2[16];
    for (int o = 0; o < 16; o++) {
        float acc = B2[o];
        #pragma unroll
        for (int i = 0; i < 32; i++) acc += t1[i] * w2[i * 16 + o];
        t2[o] = fmaxf(acc, 0.0f);
    }
    float t3[8];
    for (int o = 0; o < 8; o++) {
        float acc = B3[o];
        #pragma unroll
        for (int i = 0; i < 16; i++) acc += t2[i] * w3[i * 8 + o];
        t3[o] = fmaxf(acc, 0.0f);
    }
    float t4[4];
    for (int o = 0; o < 4; o++) {
        float acc = B4[o];
        #pragma unroll
        for (int i = 0; i < 8; i++) acc += t3[i] * w4[i * 4 + o];
        t4[o] = fmaxf(acc, 0.0f);
    }
    float zf = B5[0];
    #pragma unroll
    for (int i = 0; i < 4; i++) zf += t4[i] * w5[i];
    out[n] = 1.0f / (1.0f + expf(-zf));
}

// ---------------- host launch ----------------

extern "C" void kernel_launch(void* const* d_in, const int* in_sizes, int n_in,
                              void* d_out, int out_size, void* d_ws, size_t ws_size,
                              hipStream_t stream) {
    const float* x   = (const float*)d_in[0];
    const int*   ei  = (const int*)d_in[1];
    const int*   src = ei;
    const int*   dst = ei + N_EDGES;
    const float* U1 = (const float*)d_in[2];  const float* c1 = (const float*)d_in[3];
    const float* W1 = (const float*)d_in[4];  const float* b1 = (const float*)d_in[5];
    const float* U2 = (const float*)d_in[6];  const float* c2 = (const float*)d_in[7];
    const float* W2 = (const float*)d_in[8];  const float* b2 = (const float*)d_in[9];
    const float* U3 = (const float*)d_in[10]; const float* c3 = (const float*)d_in[11];
    const float* W3 = (const float*)d_in[12]; const float* b3 = (const float*)d_in[13];
    const float* lw1 = (const float*)d_in[14]; const float* lb1 = (const float*)d_in[15];
    const float* lw2 = (const float*)d_in[16]; const float* lb2 = (const float*)d_in[17];
    const float* lw3 = (const float*)d_in[18]; const float* lb3 = (const float*)d_in[19];
    const float* lw4 = (const float*)d_in[20]; const float* lb4 = (const float*)d_in[21];
    const float* lw5 = (const float*)d_in[22]; const float* lb5 = (const float*)d_in[23];

    char* ws = (char*)d_ws;
    size_t off = 0;
    auto alloc = [&](size_t bytes) -> void* {
        void* ptr = (void*)(ws + off);
        off += (bytes + 255) & ~(size_t)255;
        return ptr;
    };
    int*      hist_rows     = (int*)alloc((size_t)NCHUNK * NBKT * 4);
    int*      bucket_cnt    = (int*)alloc((size_t)(NBKT + 1) * 4);
    int*      bucket_base   = (int*)alloc((size_t)(NBKT + 1) * 4);
    int*      bucket_cursor = (int*)alloc((size_t)NBKT * 4);
    int*      csr_tmp       = (int*)alloc((size_t)N_EDGES * 4);
    int*      rowptr        = (int*)alloc(((size_t)N_NODES + 1) * 4);
    int*      csr_src       = (int*)alloc((size_t)N_EDGES * 4);
    float*    p             = (float*)alloc((size_t)N_NODES * 4 * 4);   // es1
    ushort_t* z             = (ushort_t*)alloc((size_t)N_NODES * 128 * 2);
    ushort_t* xbf           = (ushort_t*)alloc((size_t)N_NODES * 16 * 2);
    ushort_t* h1bf          = (ushort_t*)alloc((size_t)N_NODES * 16 * 2);
    uchar_t*  h2f8          = (uchar_t*)alloc((size_t)N_NODES * 32);
    ushort_t* h3bf          = (ushort_t*)alloc((size_t)N_NODES * 64 * 2);
    (void)ws_size;
    // de-alias esnext from es (cross-block WAR hazard): es2 lives in z's space
    // (z dead until zgather), es3 in h3bf's space (h3bf written only by post).
    float* es2 = (float*)z;
    float* es3 = (float*)h3bf;

    const int B = 256;

    // ---- CSR build ----
    bhist_pcast_kernel<<<NCHUNK + GN + 1, B, 0, stream>>>(dst, hist_rows, x, U1, p, xbf,
                                                          bucket_cnt);
    ksum_kernel<<<NRB, B, 0, stream>>>(hist_rows, bucket_cnt);
    bscan_kernel<<<1, 512, 0, stream>>>(bucket_cnt, bucket_base, bucket_cursor);
    partition_kernel<<<NCHUNK, B, 0, stream>>>(src, dst, bucket_cursor, csr_tmp);
    bucket_build_kernel<<<NBKT, B, 0, stream>>>(bucket_base, csr_tmp, rowptr, csr_src);

    const int ZG16 = (N_NODES + 63) / 64;    // 1563 (NPB=64)
    const int ZG32 = (N_NODES + 31) / 32;    // 3125 (NPB=32)
    const int NPB3 = 4 * (256 / (64 / 4));   // 64

    // ---- conv1 fused: gather(xbf) + GEMM(W1) -> bf16 h1 + es2 ----
    conv_fused_kernel<16, 16, 0><<<ZG16, B, 0, stream>>>(
        rowptr, csr_src, p, c1, xbf, W1, b1, h1bf, nullptr, U2, es2);

    // ---- conv2 fused: gather(h1bf) + GEMM(W2) -> fp8 h2 + es3 ----
    conv_fused_kernel<16, 32, 1><<<ZG16, B, 0, stream>>>(
        rowptr, csr_src, es2, c2, h1bf, W2, b2, nullptr, h2f8, U3, es3);

    // ---- conv3: fp8 gather -> z(bf16); post3 -> bf16 h3; tail -> sigmoid ----
    zgather_kernel<32><<<ZG32, B, 0, stream>>>(rowptr, csr_src, es3, c3, h2f8, z);
    post_kernel<32, 64><<<(N_NODES + NPB3 - 1) / NPB3, B, 0, stream>>>(z, W3, b3, h3bf);
    tail_kernel<<<GN, B, 0, stream>>>(h3bf, lw1, lb1, lw2, lb2, lw3, lb3,
                                      lw4, lb4, lw5, lb5, (float*)d_out);
}

// Round 9
// 316.248 us; speedup vs baseline: 1.1024x; 1.0127x over previous
//
#include <hip/hip_runtime.h>
#include <math.h>

#define N_NODES 100000
#define N_EDGES 1600000
#define HEADS 4
#define NBKT ((N_NODES + 255) / 256)
#define CHUNK_E 4096
#define NCHUNK ((N_EDGES + CHUNK_E - 1) / CHUNK_E)
#define GN ((N_NODES + 255) / 256)
#define SUM_ROWS 16
#define NRB ((NCHUNK + SUM_ROWS - 1) / SUM_ROWS)
#define RSTRIDE 48   // packed record: row 32B + es 16B (no pad; footprint == R21)

typedef unsigned short ushort_t;
typedef unsigned char  uchar_t;

__device__ __forceinline__ ushort_t f2bf(float x) {
    unsigned u = __float_as_uint(x);
    u += 0x7FFF + ((u >> 16) & 1);
    return (ushort_t)(u >> 16);
}
__device__ __forceinline__ float bf2f(ushort_t v) {
    return __uint_as_float(((unsigned)v) << 16);
}
__device__ __forceinline__ void unpack2(unsigned u, float& lo, float& hi) {
    lo = __uint_as_float(u << 16);
    hi = __uint_as_float(u & 0xffff0000u);
}
// unsigned e5m3 fp8 (ReLU outputs only)
__device__ __forceinline__ uchar_t f2fp8(float x) {
    if (x <= 0.0f) return 0;
    unsigned u = __float_as_uint(x) + (1u << 19);
    int e = (int)(u >> 23) - 127 + 15;
    if (e <= 0) return 0;
    if (e > 31) return (uchar_t)255;
    return (uchar_t)((e << 3) | ((u >> 20) & 7));
}
__device__ __forceinline__ float fp8d(uchar_t b) {
    unsigned v = (((unsigned)(b >> 3) + 112u) << 23) | ((unsigned)(b & 7) << 20);
    return (b == 0) ? 0.0f : __uint_as_float(v);
}

// ---------------- K1: per-chunk histogram rows + crec1 build + bucket_cnt zero ----
// R24: crec layout (48B packed): [0,32) feature row (bf16 x16 or fp8 x32),
// [32,48) es[4]=exp(p[h]) fp32.  One record read serves BOTH q-phase and
// accumulate (row stashed to LDS in q-phase): random L1-misses 2 -> ~1.5/edge,
// footprint unchanged (4.8MB, L2-fits) — the confound-free test of R22's
// miss-count hypothesis.

__global__ __launch_bounds__(256) void bhist_pcast_kernel(
        const int* __restrict__ dst, int* __restrict__ hist_rows,
        const float* __restrict__ x, const float* __restrict__ U,
        char* __restrict__ crec1, int* __restrict__ bucket_cnt)
{
    __shared__ int h[NBKT];
    if (blockIdx.x < NCHUNK) {
        for (int i = threadIdx.x; i < NBKT; i += 256) h[i] = 0;
        __syncthreads();
        int base = blockIdx.x * CHUNK_E;
        #pragma unroll
        for (int j = 0; j < CHUNK_E / 256; j++) {
            int e = base + j * 256 + threadIdx.x;
            if (e < N_EDGES) atomicAdd(&h[dst[e] >> 8], 1);
        }
        __syncthreads();
        for (int i = threadIdx.x; i < NBKT; i += 256)
            hist_rows[(size_t)blockIdx.x * NBKT + i] = h[i];
    } else if (blockIdx.x < NCHUNK + GN) {
        int n = (blockIdx.x - NCHUNK) * 256 + threadIdx.x;
        if (n >= N_NODES) return;
        float a0 = 0, a1 = 0, a2 = 0, a3 = 0;
        const float* hr = x + (size_t)n * 16;
        float xv[16];
        #pragma unroll
        for (int f = 0; f < 16; f++) {
            xv[f] = hr[f];
            a0 += xv[f] * U[f * 4 + 0];
            a1 += xv[f] * U[f * 4 + 1];
            a2 += xv[f] * U[f * 4 + 2];
            a3 += xv[f] * U[f * 4 + 3];
        }
        char* rec = crec1 + (size_t)n * RSTRIDE;
        #pragma unroll
        for (int j = 0; j < 4; j++) {
            ushort4 u;
            u.x = f2bf(xv[4 * j + 0]); u.y = f2bf(xv[4 * j + 1]);
            u.z = f2bf(xv[4 * j + 2]); u.w = f2bf(xv[4 * j + 3]);
            *(ushort4*)(rec + 8 * j) = u;
        }
        *(float4*)(rec + 32) =
            make_float4(__expf(a0), __expf(a1), __expf(a2), __expf(a3));
    } else {
        for (int i = threadIdx.x; i < NBKT; i += 256) bucket_cnt[i] = 0;
    }
}

// ---------------- K2a: parallel column-sum ----

__global__ __launch_bounds__(256) void ksum_kernel(const int* __restrict__ hist_rows,
                                                   int* __restrict__ bucket_cnt) {
    int r0 = blockIdx.x * SUM_ROWS;
    int r1 = min(r0 + SUM_ROWS, NCHUNK);
    for (int i = threadIdx.x; i < NBKT; i += 256) {
        int v = 0;
        for (int r = r0; r < r1; r++) v += hist_rows[(size_t)r * NBKT + i];
        if (v) atomicAdd(&bucket_cnt[i], v);
    }
}

// ---------------- K2b: exclusive scan -> base + cursor ----

__global__ __launch_bounds__(512) void bscan_kernel(const int* __restrict__ bucket_cnt,
                                                    int* __restrict__ bucket_base,
                                                    int* __restrict__ bucket_cursor) {
    __shared__ int tmp[512];
    int i = threadIdx.x;
    int v = (i < NBKT) ? bucket_cnt[i] : 0;
    tmp[i] = v;
    __syncthreads();
    for (int off = 1; off < 512; off <<= 1) {
        int t = (i >= off) ? tmp[i - off] : 0;
        __syncthreads();
        tmp[i] += t;
        __syncthreads();
    }
    int excl = tmp[i] - v;
    if (i < NBKT) { bucket_base[i] = excl; bucket_cursor[i] = excl; }
    if (i == NBKT) bucket_base[NBKT] = N_EDGES;
}

// ---------------- K3: partition into coarse buckets; packed = (dst&255)<<20 | src ----

__global__ __launch_bounds__(256) void partition_kernel(const int* __restrict__ src,
                                                        const int* __restrict__ dst,
                                                        int* __restrict__ bucket_cursor,
                                                        int* __restrict__ csr_tmp) {
    constexpr int EPT = CHUNK_E / 256;
    __shared__ int h[NBKT];
    __shared__ int gbase[NBKT];
    __shared__ int rcnt[NBKT];
    for (int i = threadIdx.x; i < NBKT; i += 256) { h[i] = 0; rcnt[i] = 0; }
    __syncthreads();
    int base = blockIdx.x * CHUNK_E;
    int d[EPT], s[EPT];
    #pragma unroll
    for (int j = 0; j < EPT; j++) {
        int e = base + j * 256 + threadIdx.x;
        d[j] = (e < N_EDGES) ? dst[e] : -1;
        s[j] = (e < N_EDGES) ? src[e] : 0;
        if (d[j] >= 0) atomicAdd(&h[d[j] >> 8], 1);
    }
    __syncthreads();
    for (int i = threadIdx.x; i < NBKT; i += 256)
        if (h[i]) gbase[i] = atomicAdd(&bucket_cursor[i], h[i]);
    __syncthreads();
    #pragma unroll
    for (int j = 0; j < EPT; j++) {
        if (d[j] >= 0) {
            int b = d[j] >> 8;
            int r = atomicAdd(&rcnt[b], 1);
            csr_tmp[gbase[b] + r] = ((d[j] & 255) << 20) | s[j];
        }
    }
}

// ---------------- K4: per-bucket build; csr_src keeps dlow packed ----

__global__ __launch_bounds__(256) void bucket_build_kernel(const int* __restrict__ bucket_base,
                                                           const int* __restrict__ csr_tmp,
                                                           int* __restrict__ rowptr,
                                                           int* __restrict__ csr_src) {
    __shared__ int cnt[256];
    __shared__ int tscan[256];
    __shared__ int exc[256];
    __shared__ int stage[8192];
    int b = blockIdx.x;
    int rbeg = bucket_base[b], rend = bucket_base[b + 1];
    int sz = rend - rbeg;
    int tid = threadIdx.x;

    cnt[tid] = 0;
    __syncthreads();
    for (int k = rbeg + tid; k < rend; k += 256) atomicAdd(&cnt[csr_tmp[k] >> 20], 1);
    __syncthreads();
    int v = cnt[tid];
    tscan[tid] = v;
    __syncthreads();
    for (int off = 1; off < 256; off <<= 1) {
        int t = (tid >= off) ? tscan[tid - off] : 0;
        __syncthreads();
        tscan[tid] += t;
        __syncthreads();
    }
    int ex = tscan[tid] - v;
    int node = b * 256 + tid;
    if (node < N_NODES) rowptr[node] = rbeg + ex;
    if (b == 0 && tid == 0) rowptr[N_NODES] = N_EDGES;
    exc[tid] = ex;
    cnt[tid] = 0;
    __syncthreads();

    if (sz <= 8192) {
        for (int k = rbeg + tid; k < rend; k += 256) {
            int pk = csr_tmp[k];
            int dl = pk >> 20;
            int r  = atomicAdd(&cnt[dl], 1);
            stage[exc[dl] + r] = pk;
        }
        __syncthreads();
        for (int i = tid; i < sz; i += 256) csr_src[rbeg + i] = stage[i];
    } else {
        for (int k = rbeg + tid; k < rend; k += 256) {
            int pk = csr_tmp[k];
            int dl = pk >> 20;
            int r  = atomicAdd(&cnt[dl], 1);
            csr_src[rbeg + exc[dl] + r] = pk;
        }
    }
}

// ---------------- fused conv (conv1/conv2): R24 = R21 + 48B-record one-read
// gather.  q-phase loads the FULL record (row 32B + es 16B, 1-2 lines, the
// 2nd/3rd load L1-hit by construction), stashes row to LDS, computes q.
// Accumulate phase reads rows from LDS ONLY — zero global gathers.
// ssrc eliminated.  Epilogue writes row + esnext into crec_out (fused).

template<int FIN, int FOUT, int OUT_FP8>
__global__ __launch_bounds__(256) void conv_fused_kernel(
        const int* __restrict__ rowptr, const int* __restrict__ csr_src,
        const char* __restrict__ crec_in,     // [N,48B] {row, es}
        const float* __restrict__ cvec,
        const float* __restrict__ W,          // [FIN, 4*FOUT]
        const float* __restrict__ b,          // [FOUT]
        char* __restrict__ crec_out,          // [N,48B] {row, esnext}
        const float* __restrict__ Unext)      // [FOUT,4]
{
    constexpr int LPN   = FIN / 4;            // 4
    constexpr int NPB   = 256 / LPN;          // 64
    constexpr int CHUNK = 512;
    constexpr int K     = 4 * FIN;            // 64
    constexpr int ZK    = K + 4;
    constexpr int HS    = FOUT + 1;
    constexpr int WSZ   = K * FOUT;
    constexpr int UNION_A = CHUNK * 16 + CHUNK * 32;   // qs + rows
    constexpr int UNION_B = NPB * ZK * 4 + NPB * HS * 4;
    constexpr int UNION   = UNION_A > UNION_B ? UNION_A : UNION_B;

    __shared__ int    sbeg[NPB + 1];
    __shared__ __align__(16) float4 pds[NPB];    // ed per local node
    __shared__ __align__(16) float  Ws[WSZ];
    __shared__ float  Uloc[FOUT * 4];
    __shared__ __align__(16) char ubuf[UNION];
    float4* qs    = (float4*)ubuf;
    char*   rows  = ubuf + CHUNK * 16;
    float*  ztile = (float*)ubuf;
    float*  hout  = (float*)(ubuf + NPB * ZK * 4);

    int tid  = threadIdx.x;
    int nloc = tid / LPN;
    int fl   = (tid - nloc * LPN) * 4;
    int n0   = blockIdx.x * NPB;
    int dbase = n0 & 255;

    float ec0 = __expf(cvec[0]), ec1 = __expf(cvec[1]);
    float ec2 = __expf(cvec[2]), ec3 = __expf(cvec[3]);

    for (int i = tid; i <= NPB; i += 256) {
        int idx = n0 + i;
        sbeg[i] = rowptr[idx > N_NODES ? N_NODES : idx];
    }
    for (int i = tid; i < NPB; i += 256) {
        int idx = n0 + i;
        float4 e = *(const float4*)(crec_in +
            (size_t)(idx < N_NODES ? idx : N_NODES - 1) * RSTRIDE + 32);
        pds[i] = make_float4(ec0 / e.x, ec1 / e.y, ec2 / e.z, ec3 / e.w);
    }
    for (int i = tid; i < WSZ; i += 256) {
        int f = i / (4 * FOUT);
        int r = i - f * (4 * FOUT);
        int h = r / FOUT;
        int o = r - h * FOUT;
        Ws[(h * FIN + f) * FOUT + o] = W[i];
    }
    for (int i = tid; i < FOUT * 4; i += 256) Uloc[i] = Unext[i];
    __syncthreads();

    int BB = sbeg[0], BE = sbeg[NPB];
    int beg = sbeg[nloc], end = sbeg[nloc + 1];

    float4 acc0 = make_float4(0, 0, 0, 0), acc1 = acc0, acc2 = acc0, acc3 = acc0;

    for (int cbase = BB; cbase < BE; cbase += CHUNK) {
        int cend = min(cbase + CHUNK, BE);
        __syncthreads();
        // q-phase: one 48B record read per edge; row -> LDS, es -> q
        for (int k = cbase + tid; k < cend; k += 256) {
            int pk = csr_src[k];
            int s  = pk & ((1 << 20) - 1);
            int nl = (pk >> 20) - dbase;
            const char* rec = crec_in + (size_t)s * RSTRIDE;
            uint4 r0 = *(const uint4*)(rec);
            uint4 r1 = *(const uint4*)(rec + 16);
            float4 e = *(const float4*)(rec + 32);
            char* rw = rows + (size_t)(k - cbase) * 32;
            *(uint4*)(rw)      = r0;
            *(uint4*)(rw + 16) = r1;
            float4 ed = pds[nl];
            float w0 = e.x * ed.x;
            float w1 = e.y * ed.y;
            float w2 = e.z * ed.z;
            float w3 = e.w * ed.w;
            float deg = (float)(sbeg[nl + 1] - sbeg[nl]);
            float inv = 1.0f / (fmaxf(deg, 1.0f) * (w0 + w1 + w2 + w3));
            qs[k - cbase] = make_float4(w0 * inv, w1 * inv, w2 * inv, w3 * inv);
        }
        __syncthreads();
        int kb = (beg > cbase ? beg : cbase) - cbase;
        int ke = (end < cend ? end : cend) - cbase;
        int k = kb;
        for (; k + 4 <= ke; k += 4) {
            uint2 r[4];
            #pragma unroll
            for (int j = 0; j < 4; j++)
                r[j] = *(const uint2*)(rows + (size_t)(k + j) * 32 + fl * 2);
            float xv[4][4];
            #pragma unroll
            for (int j = 0; j < 4; j++) {
                unpack2(r[j].x, xv[j][0], xv[j][1]);
                unpack2(r[j].y, xv[j][2], xv[j][3]);
            }
            #pragma unroll
            for (int j = 0; j < 4; j++) {
                float4 q = qs[k + j];
                acc0.x += q.x * xv[j][0]; acc0.y += q.x * xv[j][1];
                acc0.z += q.x * xv[j][2]; acc0.w += q.x * xv[j][3];
                acc1.x += q.y * xv[j][0]; acc1.y += q.y * xv[j][1];
                acc1.z += q.y * xv[j][2]; acc1.w += q.y * xv[j][3];
                acc2.x += q.z * xv[j][0]; acc2.y += q.z * xv[j][1];
                acc2.z += q.z * xv[j][2]; acc2.w += q.z * xv[j][3];
                acc3.x += q.w * xv[j][0]; acc3.y += q.w * xv[j][1];
                acc3.z += q.w * xv[j][2]; acc3.w += q.w * xv[j][3];
            }
        }
        for (; k < ke; k++) {
            float x0, x1, x2, x3;
            uint2 r = *(const uint2*)(rows + (size_t)k * 32 + fl * 2);
            unpack2(r.x, x0, x1);
            unpack2(r.y, x2, x3);
            float4 q = qs[k];
            acc0.x += q.x * x0; acc0.y += q.x * x1; acc0.z += q.x * x2; acc0.w += q.x * x3;
            acc1.x += q.y * x0; acc1.y += q.y * x1; acc1.z += q.y * x2; acc1.w += q.y * x3;
            acc2.x += q.z * x0; acc2.y += q.z * x1; acc2.z += q.z * x2; acc2.w += q.z * x3;
            acc3.x += q.w * x0; acc3.y += q.w * x1; acc3.z += q.w * x2; acc3.w += q.w * x3;
        }
    }

    __syncthreads();
    {
        float* zr = ztile + nloc * ZK;
        *(float4*)(zr + 0 * FIN + fl) = acc0;
        *(float4*)(zr + 1 * FIN + fl) = acc1;
        *(float4*)(zr + 2 * FIN + fl) = acc2;
        *(float4*)(zr + 3 * FIN + fl) = acc3;
    }
    __syncthreads();

    constexpr int OQ  = FOUT / 4;
    constexpr int QPT = (NPB * OQ) / 256;
    #pragma unroll
    for (int rq = 0; rq < QPT; rq++) {
        int idx = tid + 256 * rq;
        int j   = idx / OQ;
        int o4  = idx - j * OQ;
        float4 acc = *(const float4*)(b + 4 * o4);
        const float* zr = ztile + j * ZK;
        #pragma unroll 4
        for (int kq = 0; kq < K / 4; kq++) {
            float4 zt = *(const float4*)(zr + 4 * kq);
            #pragma unroll
            for (int jj = 0; jj < 4; jj++) {
                float4 wv = *(const float4*)(Ws + (4 * kq + jj) * FOUT + 4 * o4);
                float s = (&zt.x)[jj];
                acc.x += s * wv.x;
                acc.y += s * wv.y;
                acc.z += s * wv.z;
                acc.w += s * wv.w;
            }
        }
        acc.x = fmaxf(acc.x, 0.0f);
        acc.y = fmaxf(acc.y, 0.0f);
        acc.z = fmaxf(acc.z, 0.0f);
        acc.w = fmaxf(acc.w, 0.0f);
        float* hr = hout + j * HS + 4 * o4;
        hr[0] = acc.x; hr[1] = acc.y; hr[2] = acc.z; hr[3] = acc.w;
        int nn = n0 + j;
        if (nn < N_NODES) {
            if (OUT_FP8) {
                unsigned pk = (unsigned)f2fp8(acc.x) | ((unsigned)f2fp8(acc.y) << 8) |
                              ((unsigned)f2fp8(acc.z) << 16) | ((unsigned)f2fp8(acc.w) << 24);
                *(unsigned*)(crec_out + (size_t)nn * RSTRIDE + 4 * o4) = pk;
            } else {
                ushort4 u;
                u.x = f2bf(acc.x); u.y = f2bf(acc.y); u.z = f2bf(acc.z); u.w = f2bf(acc.w);
                *(ushort4*)(crec_out + (size_t)nn * RSTRIDE + 8 * o4) = u;
            }
        }
    }

    __syncthreads();
    if (tid < NPB) {
        int nn = n0 + tid;
        if (nn < N_NODES) {
            float a0 = 0, a1 = 0, a2 = 0, a3 = 0;
            const float* hr = hout + tid * HS;
            #pragma unroll
            for (int ff = 0; ff < FOUT; ff++) {
                float xv = hr[ff];
                a0 += xv * Uloc[ff * 4 + 0];
                a1 += xv * Uloc[ff * 4 + 1];
                a2 += xv * Uloc[ff * 4 + 2];
                a3 += xv * Uloc[ff * 4 + 3];
            }
            *(float4*)(crec_out + (size_t)nn * RSTRIDE + 32) =
                make_float4(__expf(a0), __expf(a1), __expf(a2), __expf(a3));
        }
    }
}

// ---------------- zgather (conv3, fp8 in crec3), z out bf16; R24 records ----

template<int FIN>
__global__ __launch_bounds__(256) void zgather_kernel(
        const int* __restrict__ rowptr, const int* __restrict__ csr_src,
        const char* __restrict__ crec_in,  // [N,48B] {fp8 row 32B, es}
        const float* __restrict__ cvec,
        ushort_t* __restrict__ z)          // [N, 4*FIN] bf16
{
    constexpr int LPN   = FIN / 4;         // 8
    constexpr int NPB   = 256 / LPN;       // 32
    constexpr int CHUNK = 512;
    __shared__ int    sbeg[NPB + 1];
    __shared__ __align__(16) float4 pds[NPB];
    __shared__ __align__(16) float4 qs[CHUNK];
    __shared__ __align__(16) char   rows[CHUNK * 32];

    int tid  = threadIdx.x;
    int nloc = tid / LPN;
    int fl   = (tid - nloc * LPN) * 4;     // fp8: byte offset into 32B row
    int n0   = blockIdx.x * NPB;
    int n    = n0 + nloc;
    int dbase = n0 & 255;

    float ec0 = __expf(cvec[0]), ec1 = __expf(cvec[1]);
    float ec2 = __expf(cvec[2]), ec3 = __expf(cvec[3]);

    for (int i = tid; i <= NPB; i += 256) {
        int idx = n0 + i;
        sbeg[i] = rowptr[idx > N_NODES ? N_NODES : idx];
    }
    for (int i = tid; i < NPB; i += 256) {
        int idx = n0 + i;
        float4 e = *(const float4*)(crec_in +
            (size_t)(idx < N_NODES ? idx : N_NODES - 1) * RSTRIDE + 32);
        pds[i] = make_float4(ec0 / e.x, ec1 / e.y, ec2 / e.z, ec3 / e.w);
    }
    __syncthreads();

    int BB = sbeg[0], BE = sbeg[NPB];
    int beg = sbeg[nloc], end = sbeg[nloc + 1];

    float4 acc0 = make_float4(0, 0, 0, 0), acc1 = acc0, acc2 = acc0, acc3 = acc0;

    for (int cbase = BB; cbase < BE; cbase += CHUNK) {
        int cend = min(cbase + CHUNK, BE);
        __syncthreads();
        for (int k = cbase + tid; k < cend; k += 256) {
            int pk = csr_src[k];
            int s  = pk & ((1 << 20) - 1);
            int nl = (pk >> 20) - dbase;
            const char* rec = crec_in + (size_t)s * RSTRIDE;
            uint4 r0 = *(const uint4*)(rec);
            uint4 r1 = *(const uint4*)(rec + 16);
            float4 e = *(const float4*)(rec + 32);
            char* rw = rows + (size_t)(k - cbase) * 32;
            *(uint4*)(rw)      = r0;
            *(uint4*)(rw + 16) = r1;
            float4 ed = pds[nl];
            float w0 = e.x * ed.x;
            float w1 = e.y * ed.y;
            float w2 = e.z * ed.z;
            float w3 = e.w * ed.w;
            float deg = (float)(sbeg[nl + 1] - sbeg[nl]);
            float inv = 1.0f / (fmaxf(deg, 1.0f) * (w0 + w1 + w2 + w3));
            qs[k - cbase] = make_float4(w0 * inv, w1 * inv, w2 * inv, w3 * inv);
        }
        __syncthreads();
        int kb = (beg > cbase ? beg : cbase) - cbase;
        int ke = (end < cend ? end : cend) - cbase;
        int k = kb;
        for (; k + 4 <= ke; k += 4) {
            unsigned r[4];
            #pragma unroll
            for (int j = 0; j < 4; j++)
                r[j] = *(const unsigned*)(rows + (size_t)(k + j) * 32 + fl);
            float xv[4][4];
            #pragma unroll
            for (int j = 0; j < 4; j++) {
                xv[j][0] = fp8d((uchar_t)(r[j] & 255));
                xv[j][1] = fp8d((uchar_t)((r[j] >> 8) & 255));
                xv[j][2] = fp8d((uchar_t)((r[j] >> 16) & 255));
                xv[j][3] = fp8d((uchar_t)(r[j] >> 24));
            }
            #pragma unroll
            for (int j = 0; j < 4; j++) {
                float4 q = qs[k + j];
                acc0.x += q.x * xv[j][0]; acc0.y += q.x * xv[j][1];
                acc0.z += q.x * xv[j][2]; acc0.w += q.x * xv[j][3];
                acc1.x += q.y * xv[j][0]; acc1.y += q.y * xv[j][1];
                acc1.z += q.y * xv[j][2]; acc1.w += q.y * xv[j][3];
                acc2.x += q.z * xv[j][0]; acc2.y += q.z * xv[j][1];
                acc2.z += q.z * xv[j][2]; acc2.w += q.z * xv[j][3];
                acc3.x += q.w * xv[j][0]; acc3.y += q.w * xv[j][1];
                acc3.z += q.w * xv[j][2]; acc3.w += q.w * xv[j][3];
            }
        }
        for (; k < ke; k++) {
            unsigned r = *(const unsigned*)(rows + (size_t)k * 32 + fl);
            float x0 = fp8d((uchar_t)(r & 255));
            float x1 = fp8d((uchar_t)((r >> 8) & 255));
            float x2 = fp8d((uchar_t)((r >> 16) & 255));
            float x3 = fp8d((uchar_t)(r >> 24));
            float4 q = qs[k];
            acc0.x += q.x * x0; acc0.y += q.x * x1; acc0.z += q.x * x2; acc0.w += q.x * x3;
            acc1.x += q.y * x0; acc1.y += q.y * x1; acc1.z += q.y * x2; acc1.w += q.y * x3;
            acc2.x += q.z * x0; acc2.y += q.z * x1; acc2.z += q.z * x2; acc2.w += q.z * x3;
            acc3.x += q.w * x0; acc3.y += q.w * x1; acc3.z += q.w * x2; acc3.w += q.w * x3;
        }
    }

    if (n < N_NODES) {
        size_t base = (size_t)n * (4 * FIN) + fl;
        ushort4 u;
        u.x = f2bf(acc0.x); u.y = f2bf(acc0.y); u.z = f2bf(acc0.z); u.w = f2bf(acc0.w);
        *(ushort4*)(z + base) = u;
        u.x = f2bf(acc1.x); u.y = f2bf(acc1.y); u.z = f2bf(acc1.z); u.w = f2bf(acc1.w);
        *(ushort4*)(z + base + FIN) = u;
        u.x = f2bf(acc2.x); u.y = f2bf(acc2.y); u.z = f2bf(acc2.z); u.w = f2bf(acc2.w);
        *(ushort4*)(z + base + 2 * FIN) = u;
        u.x = f2bf(acc3.x); u.y = f2bf(acc3.y); u.z = f2bf(acc3.z); u.w = f2bf(acc3.w);
        *(ushort4*)(z + base + 3 * FIN) = u;
    }
}

// ---------------- post3: z(bf16) -> bf16 h3 (R16-proven standalone) ----------------

template<int FIN, int FOUT>
__global__ __launch_bounds__(256, 4) void post_kernel(
        const ushort_t* __restrict__ z,   // [N, 4*FIN] bf16
        const float* __restrict__ W,      // [FIN, 4*FOUT]
        const float* __restrict__ b,      // [FOUT]
        ushort_t* __restrict__ out_bf)    // [N, FOUT]
{
    constexpr int K   = 4 * FIN;
    constexpr int OL  = FOUT / 4;
    constexpr int NPB = 4 * (256 / OL);
    constexpr int WSZ = FIN * 4 * FOUT;
    __shared__ __align__(16) float Wp[WSZ];
    for (int i = threadIdx.x; i < WSZ; i += 256) {
        int f = i / (4 * FOUT);
        int r = i - f * (4 * FOUT);
        int h = r / FOUT;
        int o = r - h * FOUT;
        Wp[(h * FIN + f) * FOUT + o] = W[i];
    }
    __syncthreads();

    int ol = threadIdx.x % OL;
    int g  = threadIdx.x / OL;
    int n0 = blockIdx.x * NPB + g * 4;

    float4 bv = *(const float4*)(b + 4 * ol);
    float4 acc[4];
    const ushort_t* zr[4];
    #pragma unroll
    for (int j = 0; j < 4; j++) {
        acc[j] = make_float4(0.f, 0.f, 0.f, 0.f);
        int nn = n0 + j; if (nn > N_NODES - 1) nn = N_NODES - 1;
        zr[j] = z + (size_t)nn * K;
    }

    #pragma unroll 2
    for (int kq = 0; kq < K / 4; kq++) {
        float zv[4][4];
        #pragma unroll
        for (int j = 0; j < 4; j++) {
            ushort4 zu = *(const ushort4*)(zr[j] + 4 * kq);
            zv[j][0] = bf2f(zu.x); zv[j][1] = bf2f(zu.y);
            zv[j][2] = bf2f(zu.z); zv[j][3] = bf2f(zu.w);
        }
        #pragma unroll
        for (int jj = 0; jj < 4; jj++) {
            float4 wv = *(const float4*)(Wp + (4 * kq + jj) * FOUT + 4 * ol);
            #pragma unroll
            for (int j = 0; j < 4; j++) {
                float s = zv[j][jj];
                acc[j].x += s * wv.x;
                acc[j].y += s * wv.y;
                acc[j].z += s * wv.z;
                acc[j].w += s * wv.w;
            }
        }
    }

    #pragma unroll
    for (int j = 0; j < 4; j++) {
        int nn = n0 + j;
        if (nn < N_NODES) {
            ushort4 u;
            u.x = f2bf(fmaxf(acc[j].x + bv.x, 0.0f));
            u.y = f2bf(fmaxf(acc[j].y + bv.y, 0.0f));
            u.z = f2bf(fmaxf(acc[j].z + bv.z, 0.0f));
            u.w = f2bf(fmaxf(acc[j].w + bv.w, 0.0f));
            *(ushort4*)(out_bf + (size_t)nn * FOUT + 4 * ol) = u;
        }
    }
}

// ---------------- fused linear tail (bf16 input): 64->32->16->8->4->1 ----------------

__global__ __launch_bounds__(256) void tail_kernel(
        const ushort_t* __restrict__ h,   // [N, 64] bf16
        const float* __restrict__ lw1, const float* __restrict__ lb1,
        const float* __restrict__ lw2, const float* __restrict__ lb2,
        const float* __restrict__ lw3, const float* __restrict__ lb3,
        const float* __restrict__ lw4, const float* __restrict__ lb4,
        const float* __restrict__ lw5, const float* __restrict__ lb5,
        float* __restrict__ out)
{
    __shared__ __align__(16) float w1[64 * 32];
    __shared__ float w2[32 * 16], w3[16 * 8], w4[8 * 4], w5[4];
    __shared__ float B1[32], B2[16], B3[8], B4[4], B5[1];
    for (int i = threadIdx.x; i < 64 * 32; i += blockDim.x) w1[i] = lw1[i];
    for (int i = threadIdx.x; i < 32 * 16; i += blockDim.x) w2[i] = lw2[i];
    for (int i = threadIdx.x; i < 16 * 8;  i += blockDim.x) w3[i] = lw3[i];
    for (int i = threadIdx.x; i < 8 * 4;   i += blockDim.x) w4[i] = lw4[i];
    for (int i = threadIdx.x; i < 4;       i += blockDim.x) w5[i] = lw5[i];
    for (int i = threadIdx.x; i < 32; i += blockDim.x) B1[i] = lb1[i];
    for (int i = threadIdx.x; i < 16; i += blockDim.x) B2[i] = lb2[i];
    for (int i = threadIdx.x; i < 8;  i += blockDim.x) B3[i] = lb3[i];
    for (int i = threadIdx.x; i < 4;  i += blockDim.x) B4[i] = lb4[i];
    if (threadIdx.x == 0) B5[0] = lb5[0];
    __syncthreads();

    int n = blockIdx.x * blockDim.x + threadIdx.x;
    if (n >= N_NODES) return;

    float a[64];
    const uint4* hrow = (const uint4*)(h + (size_t)n * 64);
    #pragma unroll
    for (int j = 0; j < 8; j++) {
        uint4 v = hrow[j];
        unpack2(v.x, a[8 * j + 0], a[8 * j + 1]);
        unpack2(v.y, a[8 * j + 2], a[8 * j + 3]);
        unpack2(v.z, a[8 * j + 4], a[8 * j + 5]);
        unpack2(v.w, a[8 * j + 6], a[8 * j + 7]);
    }

    float t1[32];
    for (int o = 0; o < 32; o++) {
        float acc = B1[o];
        #pragma unroll
        for (int i = 0; i < 64; i++) acc += a[i] * w1[i * 32 + o];
        t1[o] = fmaxf(acc, 0.0f);
    }
    float t2[16];
    for (int o = 0; o < 16; o++) {
        float acc = B2[o];
        #pragma unroll
        for (int i = 0; i < 32; i++) acc += t1[i] * w2[i * 16 + o];
        t2[o] = fmaxf(acc, 0.0f);
    }
    float t3[8];
    for (int o = 0; o < 8; o++) {
        float acc = B3[o];
        #pragma unroll
        for (int i = 0; i < 16; i++) acc += t2[i] * w3[i * 8 + o];
        t3[o] = fmaxf(acc, 0.0f);
    }
    float t4[4];
    for (int o = 0; o < 4; o++) {
        float acc = B4[o];
        #pragma unroll
        for (int i = 0; i < 8; i++) acc += t3[i] * w4[i * 4 + o];
        t4[o] = fmaxf(acc, 0.0f);
    }
    float zf = B5[0];
    #pragma unroll
    for (int i = 0; i < 4; i++) zf += t4[i] * w5[i];
    out[n] = 1.0f / (1.0f + expf(-zf));
}

// ---------------- host launch ----------------

extern "C" void kernel_launch(void* const* d_in, const int* in_sizes, int n_in,
                              void* d_out, int out_size, void* d_ws, size_t ws_size,
                              hipStream_t stream) {
    const float* x   = (const float*)d_in[0];
    const int*   ei  = (const int*)d_in[1];
    const int*   src = ei;
    const int*   dst = ei + N_EDGES;
    const float* U1 = (const float*)d_in[2];  const float* c1 = (const float*)d_in[3];
    const float* W1 = (const float*)d_in[4];  const float* b1 = (const float*)d_in[5];
    const float* U2 = (const float*)d_in[6];  const float* c2 = (const float*)d_in[7];
    const float* W2 = (const float*)d_in[8];  const float* b2 = (const float*)d_in[9];
    const float* U3 = (const float*)d_in[10]; const float* c3 = (const float*)d_in[11];
    const float* W3 = (const float*)d_in[12]; const float* b3 = (const float*)d_in[13];
    const float* lw1 = (const float*)d_in[14]; const float* lb1 = (const float*)d_in[15];
    const float* lw2 = (const float*)d_in[16]; const float* lb2 = (const float*)d_in[17];
    const float* lw3 = (const float*)d_in[18]; const float* lb3 = (const float*)d_in[19];
    const float* lw4 = (const float*)d_in[20]; const float* lb4 = (const float*)d_in[21];
    const float* lw5 = (const float*)d_in[22]; const float* lb5 = (const float*)d_in[23];

    char* ws = (char*)d_ws;
    size_t off = 0;
    auto alloc = [&](size_t bytes) -> void* {
        void* ptr = (void*)(ws + off);
        off += (bytes + 255) & ~(size_t)255;
        return ptr;
    };
    int*      hist_rows     = (int*)alloc((size_t)NCHUNK * NBKT * 4);
    int*      bucket_cnt    = (int*)alloc((size_t)(NBKT + 1) * 4);
    int*      bucket_base   = (int*)alloc((size_t)(NBKT + 1) * 4);
    int*      bucket_cursor = (int*)alloc((size_t)NBKT * 4);
    int*      csr_tmp       = (int*)alloc((size_t)N_EDGES * 4);
    int*      rowptr        = (int*)alloc(((size_t)N_NODES + 1) * 4);
    int*      csr_src       = (int*)alloc((size_t)N_EDGES * 4);
    char*     crec1         = (char*)alloc((size_t)N_NODES * RSTRIDE);
    char*     crec2         = (char*)alloc((size_t)N_NODES * RSTRIDE);
    char*     crec3         = (char*)alloc((size_t)N_NODES * RSTRIDE);
    ushort_t* z             = (ushort_t*)alloc((size_t)N_NODES * 128 * 2);
    ushort_t* h3bf          = (ushort_t*)alloc((size_t)N_NODES * 64 * 2);
    (void)ws_size;

    const int B = 256;

    // ---- CSR build + crec1 (x row + es1) ----
    bhist_pcast_kernel<<<NCHUNK + GN + 1, B, 0, stream>>>(dst, hist_rows, x, U1,
                                                          crec1, bucket_cnt);
    ksum_kernel<<<NRB, B, 0, stream>>>(hist_rows, bucket_cnt);
    bscan_kernel<<<1, 512, 0, stream>>>(bucket_cnt, bucket_base, bucket_cursor);
    partition_kernel<<<NCHUNK, B, 0, stream>>>(src, dst, bucket_cursor, csr_tmp);
    bucket_build_kernel<<<NBKT, B, 0, stream>>>(bucket_base, csr_tmp, rowptr, csr_src);

    const int ZG16 = (N_NODES + 63) / 64;    // NPB=64
    const int ZG32 = (N_NODES + 31) / 32;    // NPB=32
    const int NPB3 = 4 * (256 / (64 / 4));   // 64

    // ---- conv1: crec1 -> crec2 {bf16 h1, es2} ----
    conv_fused_kernel<16, 16, 0><<<ZG16, B, 0, stream>>>(
        rowptr, csr_src, crec1, c1, W1, b1, crec2, U2);

    // ---- conv2: crec2 -> crec3 {fp8 h2, es3} ----
    conv_fused_kernel<16, 32, 1><<<ZG16, B, 0, stream>>>(
        rowptr, csr_src, crec2, c2, W2, b2, crec3, U3);

    // ---- conv3: fp8 gather -> z(bf16); post3 -> bf16 h3; tail -> sigmoid ----
    zgather_kernel<32><<<ZG32, B, 0, stream>>>(rowptr, csr_src, crec3, c3, z);
    post_kernel<32, 64><<<(N_NODES + NPB3 - 1) / NPB3, B, 0, stream>>>(z, W3, b3, h3bf);
    tail_kernel<<<GN, B, 0, stream>>>(h3bf, lw1, lb1, lw2, lb2, lw3, lb3,
                                      lw4, lb4, lw5, lb5, (float*)d_out);
}